// Round 1
// baseline (1767.851 us; speedup 1.0000x reference)
//
#include <hip/hip_runtime.h>

#define NPTS 2000
#define NBATCH 8
#define NC 256
#define NW 128
#define NK 10
#define NROWS (NBATCH * NPTS)

__device__ __forceinline__ float dot4(float4 a, float4 b) {
    return a.x*b.x + a.y*b.y + a.z*b.z + a.w*b.w;
}
__device__ __forceinline__ float4 relu4(float4 a) {
    return make_float4(fmaxf(a.x,0.f), fmaxf(a.y,0.f), fmaxf(a.z,0.f), fmaxf(a.w,0.f));
}

// ---------------- Kernel 0: row squared-norms xx[b,n] ----------------
__global__ __launch_bounds__(256) void k_xx(const float* __restrict__ x,
                                            float* __restrict__ xx) {
    int r = blockIdx.x * blockDim.x + threadIdx.x;
    if (r >= NROWS) return;
    int b = r / NPTS, n = r % NPTS;
    const float* xp = x + (size_t)b * NC * NPTS + n;
    float s = 0.f;
    #pragma unroll 8
    for (int c = 0; c < NC; ++c) {
        float v = xp[(size_t)c * NPTS];
        s = fmaf(v, v, s);
    }
    xx[r] = s;
}

// ---------------- Kernel A: row GEMM -> T1r / P / Q ----------------
// M=16000 rows, K=256, 128 cols per sel. grid = (500 row-tiles, 3 sels)
// sel 0: T1r = relu(tW1*x + tb1); sel 1: P = A*x; sel 2: Q = B*x + sb1
__global__ __launch_bounds__(256) void k_rowgemm(
    const float* __restrict__ x,
    const float* __restrict__ tW1, const float* __restrict__ tb1,
    const float* __restrict__ sW1, const float* __restrict__ sb1,
    float* __restrict__ T1r, float* __restrict__ P, float* __restrict__ Q)
{
    __shared__ float Xs[32][34];    // [kk][i]
    __shared__ float Ws[32][132];   // [kk][j]
    const int t  = threadIdx.x;
    const int r0 = blockIdx.x * 32;
    const int sel = blockIdx.y;
    const int jq = t & 15,  iq = t >> 4;
    const int j0 = jq * 8,  i0 = iq * 2;

    float acc[2][8];
    #pragma unroll
    for (int a = 0; a < 2; ++a)
        #pragma unroll
        for (int q = 0; q < 8; ++q) acc[a][q] = 0.f;

    const int li = t & 31;   // X load: row
    const int lk = t >> 5;   // X load: kk group 0..7
    const int rl = r0 + li;
    const int lb = rl / NPTS, ln = rl % NPTS;

    for (int c0 = 0; c0 < NC; c0 += 32) {
        #pragma unroll
        for (int p = 0; p < 4; ++p) {
            int kk = lk + p * 8;
            Xs[kk][li] = x[((size_t)lb * NC + c0 + kk) * NPTS + ln];
        }
        #pragma unroll
        for (int jj = 0; jj < 16; ++jj) {
            int j = jj * 8 + lk;
            int c = c0 + li;
            float w;
            if (sel == 0)      w = tW1[j * NC + c];
            else if (sel == 1) w = sW1[j * (2*NC) + c];
            else               w = sW1[j * (2*NC) + NC + c];
            Ws[li][j] = w;
        }
        __syncthreads();
        #pragma unroll 8
        for (int kk = 0; kk < 32; ++kk) {
            const float2 xv = *(const float2*)&Xs[kk][i0];
            const float4 w0 = *(const float4*)&Ws[kk][j0];
            const float4 w1 = *(const float4*)&Ws[kk][j0 + 4];
            float w[8] = {w0.x,w0.y,w0.z,w0.w,w1.x,w1.y,w1.z,w1.w};
            #pragma unroll
            for (int q = 0; q < 8; ++q) {
                acc[0][q] = fmaf(xv.x, w[q], acc[0][q]);
                acc[1][q] = fmaf(xv.y, w[q], acc[1][q]);
            }
        }
        __syncthreads();
    }

    #pragma unroll
    for (int a = 0; a < 2; ++a) {
        const int r = r0 + i0 + a;
        float o[8];
        #pragma unroll
        for (int q = 0; q < 8; ++q) {
            float v = acc[a][q];
            if (sel == 0)      { v += tb1[j0+q]; v = fmaxf(v, 0.f); }
            else if (sel == 2) { v += sb1[j0+q]; }
            o[q] = v;
        }
        float* dst = (sel==0 ? T1r : (sel==1 ? P : Q)) + (size_t)r * NW + j0;
        *(float4*)dst       = make_float4(o[0],o[1],o[2],o[3]);
        *(float4*)(dst + 4) = make_float4(o[4],o[5],o[6],o[7]);
    }
}

// ---------------- Kernel B: fused pairwise-distance + per-row top-10 ----------------
// grid = 8 batches * 125 row-tiles (16 rows). j streamed in 16 tiles of 128 (padded 2048).
__global__ __launch_bounds__(256) void k_topk(
    const float* __restrict__ x, const float* __restrict__ xx,
    int* __restrict__ tk)
{
    __shared__ float Xi[NC][16];        // [c][i]
    __shared__ float Xjs[32][132];      // [kk][j]
    __shared__ float cval[16][16][10];
    __shared__ int   cidx[16][16][10];

    const int t  = threadIdx.x;
    const int b  = blockIdx.x / 125;
    const int i0 = (blockIdx.x % 125) * 16;
    const int il = t >> 4;    // my row 0..15
    const int jl = t & 15;    // my j lane 0..15
    const int jl8 = jl * 8;

    {   // load Xi (16 rows x 256 c)
        const int i = t & 15, cc = t >> 4;
        const size_t base = (size_t)b * NC * NPTS + (i0 + i);
        #pragma unroll
        for (int p = 0; p < 16; ++p) {
            int c = cc + p * 16;
            Xi[c][i] = x[base + (size_t)c * NPTS];
        }
    }
    __syncthreads();

    float vals[10]; int idxs[10];
    #pragma unroll
    for (int q = 0; q < 10; ++q) { vals[q] = -3.0e38f; idxs[q] = 0x7fffffff; }
    const float xxi = xx[b * NPTS + i0 + il];

    const int ljj = t & 127, lch = t >> 7;   // Xj load mapping
    for (int jt = 0; jt < 16; ++jt) {
        const int j0t = jt * 128;
        float acc[8];
        #pragma unroll
        for (int q = 0; q < 8; ++q) acc[q] = 0.f;

        for (int c0 = 0; c0 < NC; c0 += 32) {
            const int jg = j0t + ljj;
            const bool okj = jg < NPTS;
            const size_t jbase = (size_t)b * NC * NPTS + jg;
            #pragma unroll
            for (int p = 0; p < 16; ++p) {
                int kk = lch + p * 2;
                Xjs[kk][ljj] = okj ? x[jbase + (size_t)(c0 + kk) * NPTS] : 0.f;
            }
            __syncthreads();
            #pragma unroll 8
            for (int kk = 0; kk < 32; ++kk) {
                const float xiv = Xi[c0 + kk][il];
                const float4 a4 = *(const float4*)&Xjs[kk][jl8];
                const float4 b4 = *(const float4*)&Xjs[kk][jl8 + 4];
                acc[0] = fmaf(xiv, a4.x, acc[0]);
                acc[1] = fmaf(xiv, a4.y, acc[1]);
                acc[2] = fmaf(xiv, a4.z, acc[2]);
                acc[3] = fmaf(xiv, a4.w, acc[3]);
                acc[4] = fmaf(xiv, b4.x, acc[4]);
                acc[5] = fmaf(xiv, b4.y, acc[5]);
                acc[6] = fmaf(xiv, b4.z, acc[6]);
                acc[7] = fmaf(xiv, b4.w, acc[7]);
            }
            __syncthreads();
        }
        // streamed sorted-insert (ascending j preserves lowest-index-on-tie)
        #pragma unroll
        for (int q = 0; q < 8; ++q) {
            const int j = j0t + jl8 + q;
            if (j < NPTS) {
                float d = 2.f * acc[q] - xx[b * NPTS + j] - xxi;
                if (d > vals[9]) {
                    float v = d; int id = j;
                    #pragma unroll
                    for (int s = 0; s < 10; ++s) {
                        if (v > vals[s]) {
                            float tv = vals[s]; vals[s] = v; v = tv;
                            int   ti = idxs[s]; idxs[s] = id; id = ti;
                        }
                    }
                }
            }
        }
    }

    #pragma unroll
    for (int q = 0; q < 10; ++q) { cval[il][jl][q] = vals[q]; cidx[il][jl][q] = idxs[q]; }
    __syncthreads();

    if (t < 16) {  // one merger thread per row: 16-way merge of sorted lists
        const int row = t;
        int ptr[16];
        #pragma unroll
        for (int q = 0; q < 16; ++q) ptr[q] = 0;
        int* op = tk + (size_t)(b * NPTS + i0 + row) * NK;
        for (int s = 0; s < NK; ++s) {
            float bv = -3.4e38f; int bi = 0x7fffffff; int bl = 0;
            for (int l = 0; l < 16; ++l) {
                if (ptr[l] < 10) {
                    float v = cval[row][l][ptr[l]];
                    int  id = cidx[row][l][ptr[l]];
                    if (v > bv || (v == bv && id < bi)) { bv = v; bi = id; bl = l; }
                }
            }
            ptr[bl]++;
            op[s] = b * NPTS + bi;   // flat row index
        }
    }
}

// ---------------- Kernel D: fused tail ----------------
// Per block: 16 points. Phase 1: Z (temporal grouped 1x3) + G2 (10 x grouped 1x1) -> LDS.
// Phase 2: 11 matvecs 128->256 with max-over-k, + bias + residual + relu -> out.
__global__ __launch_bounds__(256) void k_fused(
    const float* __restrict__ x,
    const int* __restrict__ nb, const int* __restrict__ tk,
    const float* __restrict__ T1r, const float* __restrict__ P, const float* __restrict__ Q,
    const float* __restrict__ tW2, const float* __restrict__ tb2,
    const float* __restrict__ sW2, const float* __restrict__ sb2,
    const float* __restrict__ tW3, const float* __restrict__ tb3,
    const float* __restrict__ sW3, const float* __restrict__ sb3,
    float* __restrict__ out)
{
    __shared__ float Zs[16][132];         //  8.4 KB
    __shared__ float G2s[160][132];       // 84.5 KB
    __shared__ float Wt[32][132];         // 16.9 KB
    __shared__ float Ws2[32][132];        // 16.9 KB

    const int t    = threadIdx.x;
    const int r0   = blockIdx.x * 16;
    const int bb   = r0 / NPTS;           // whole block in one batch (2000 % 16 == 0)
    const int n0   = r0 % NPTS;

    // ---- phase 1 ----
    {
        const int o    = t & 127;
        const int half = t >> 7;
        const int g4   = o & ~3;

        const float4 f0 = *(const float4*)&tW2[o*12];
        const float4 f1 = *(const float4*)&tW2[o*12 + 4];
        const float4 f2 = *(const float4*)&tW2[o*12 + 8];
        float4 wt[3];
        wt[0] = make_float4(f0.x, f0.w, f1.z, f2.y);   // W[o][c][t=0], c=0..3
        wt[1] = make_float4(f0.y, f1.x, f1.w, f2.z);   // t=1
        wt[2] = make_float4(f0.z, f1.y, f2.x, f2.w);   // t=2
        const float4 wsw = *(const float4*)&sW2[o*4];
        const float tb2o = tb2[o], sb2o = sb2[o];

        for (int ptl = 0; ptl < 8; ++ptl) {
            const int pt = half * 8 + ptl;
            const int r  = r0 + pt;
            // temporal: h_t = relu'd T1r rows of the 3 graph neighbors
            float z = tb2o;
            #pragma unroll
            for (int tt = 0; tt < 3; ++tt) {
                const int nr = nb[r*3 + tt];
                const float4 hv = *(const float4*)&T1r[(size_t)nr * NW + g4];
                z += dot4(wt[tt], hv);
            }
            Zs[pt][o] = fmaxf(z, 0.f);
            // semantic: g2 for the 10 kNN neighbors
            const float4 qf = *(const float4*)&Q[(size_t)r * NW + g4];
            for (int k = 0; k < NK; ++k) {
                const int nr2 = tk[r*NK + k];
                const float4 pf = *(const float4*)&P[(size_t)nr2 * NW + g4];
                const float4 g1 = relu4(make_float4(pf.x+qf.x, pf.y+qf.y,
                                                    pf.z+qf.z, pf.w+qf.w));
                const float g2 = dot4(wsw, g1) + sb2o;
                G2s[pt*NK + k][o] = fmaxf(g2, 0.f);
            }
        }
    }
    __syncthreads();

    // ---- phase 2 ----
    const int o2l = t >> 3;   // 0..31
    const int pth = t & 7;    // 0..7
    for (int chunk = 0; chunk < 8; ++chunk) {
        {   // stage 32x128 chunks of tW3 and sW3
            const int row = t >> 3, c4 = t & 7;
            #pragma unroll
            for (int qq = 0; qq < 4; ++qq) {
                const int c = c4*16 + qq*4;
                *(float4*)&Wt[row][c]  = *(const float4*)&tW3[(size_t)(chunk*32+row)*NW + c];
                *(float4*)&Ws2[row][c] = *(const float4*)&sW3[(size_t)(chunk*32+row)*NW + c];
            }
        }
        __syncthreads();

        float res[2][11];
        #pragma unroll
        for (int h = 0; h < 2; ++h)
            #pragma unroll
            for (int s = 0; s < 11; ++s) res[h][s] = 0.f;

        #pragma unroll 2
        for (int c4 = 0; c4 < 32; ++c4) {
            const int c = c4 * 4;
            const float4 w3t = *(const float4*)&Wt[o2l][c];
            const float4 w3s = *(const float4*)&Ws2[o2l][c];
            #pragma unroll
            for (int h = 0; h < 2; ++h) {
                const int pt = pth + 8*h;
                const float4 z4 = *(const float4*)&Zs[pt][c];
                res[h][0] += dot4(w3t, z4);
                #pragma unroll
                for (int k = 0; k < NK; ++k) {
                    const float4 g4v = *(const float4*)&G2s[pt*NK + k][c];
                    res[h][1+k] += dot4(w3s, g4v);
                }
            }
        }

        const int o2 = chunk*32 + o2l;
        #pragma unroll
        for (int h = 0; h < 2; ++h) {
            const int pt = pth + 8*h;
            const int n  = n0 + pt;
            float sv = res[h][1];
            #pragma unroll
            for (int k = 1; k < NK; ++k) sv = fmaxf(sv, res[h][1+k]);
            const size_t gi = ((size_t)bb * NC + o2) * NPTS + n;
            const float v = res[h][0] + tb3[o2] + sv + sb3[o2] + x[gi];
            out[gi] = fmaxf(v, 0.f);
        }
        __syncthreads();
    }
}

extern "C" void kernel_launch(void* const* d_in, const int* in_sizes, int n_in,
                              void* d_out, int out_size, void* d_ws, size_t ws_size,
                              hipStream_t stream) {
    (void)in_sizes; (void)n_in; (void)out_size; (void)ws_size;
    const float* x   = (const float*)d_in[0];
    // d_in[1] seg_lens: unused (neighbor_idx is precomputed)
    const int*   nb  = (const int*)d_in[2];
    const float* tW1 = (const float*)d_in[3];
    const float* tb1 = (const float*)d_in[4];
    const float* tW2 = (const float*)d_in[5];
    const float* tb2 = (const float*)d_in[6];
    const float* tW3 = (const float*)d_in[7];
    const float* tb3 = (const float*)d_in[8];
    const float* sW1 = (const float*)d_in[9];
    const float* sb1 = (const float*)d_in[10];
    const float* sW2 = (const float*)d_in[11];
    const float* sb2 = (const float*)d_in[12];
    const float* sW3 = (const float*)d_in[13];
    const float* sb3 = (const float*)d_in[14];
    float* out = (float*)d_out;

    float* ws  = (float*)d_ws;
    float* T1r = ws;                                    // 16000*128
    float* P   = ws + (size_t)NROWS * NW;               // 16000*128
    float* Q   = ws + (size_t)2 * NROWS * NW;           // 16000*128
    float* xxp = ws + (size_t)3 * NROWS * NW;           // 16000
    int*   tk  = (int*)(ws + (size_t)3 * NROWS * NW + NROWS);  // 16000*10 ints

    k_xx<<<(NROWS + 255) / 256, 256, 0, stream>>>(x, xxp);
    k_rowgemm<<<dim3(NROWS / 32, 3), 256, 0, stream>>>(x, tW1, tb1, sW1, sb1, T1r, P, Q);
    k_topk<<<NBATCH * (NPTS / 16), 256, 0, stream>>>(x, xxp, tk);
    k_fused<<<NROWS / 16, 256, 0, stream>>>(x, nb, tk, T1r, P, Q,
                                            tW2, tb2, sW2, sb2, tW3, tb3, sW3, sb3, out);
}

// Round 2
// 826.168 us; speedup vs baseline: 2.1398x; 2.1398x over previous
//
#include <hip/hip_runtime.h>

#define NPTS 2000
#define NBATCH 8
#define NC 256
#define NW 128
#define NK 10
#define NROWS (NBATCH * NPTS)
#define TKTILES 63   // ceil(2000/32)

__device__ __forceinline__ float dot4(float4 a, float4 b) {
    return a.x*b.x + a.y*b.y + a.z*b.z + a.w*b.w;
}
__device__ __forceinline__ float4 relu4(float4 a) {
    return make_float4(fmaxf(a.x,0.f), fmaxf(a.y,0.f), fmaxf(a.z,0.f), fmaxf(a.w,0.f));
}
__device__ __forceinline__ float4 add4(float4 a, float4 b) {
    return make_float4(a.x+b.x, a.y+b.y, a.z+b.z, a.w+b.w);
}

// ---------------- Kernel 0: row squared-norms xx[b,n] ----------------
__global__ __launch_bounds__(256) void k_xx(const float* __restrict__ x,
                                            float* __restrict__ xx) {
    int r = blockIdx.x * blockDim.x + threadIdx.x;
    if (r >= NROWS) return;
    int b = r / NPTS, n = r % NPTS;
    const float* xp = x + (size_t)b * NC * NPTS + n;
    float s = 0.f;
    #pragma unroll 8
    for (int c = 0; c < NC; ++c) {
        float v = xp[(size_t)c * NPTS];
        s = fmaf(v, v, s);
    }
    xx[r] = s;
}

// ---------------- Kernel A: row GEMM -> T1r / P / Q ----------------
__global__ __launch_bounds__(256) void k_rowgemm(
    const float* __restrict__ x,
    const float* __restrict__ tW1, const float* __restrict__ tb1,
    const float* __restrict__ sW1, const float* __restrict__ sb1,
    float* __restrict__ T1r, float* __restrict__ P, float* __restrict__ Q)
{
    __shared__ float Xs[32][34];
    __shared__ float Ws[32][132];
    const int t  = threadIdx.x;
    const int r0 = blockIdx.x * 32;
    const int sel = blockIdx.y;
    const int jq = t & 15,  iq = t >> 4;
    const int j0 = jq * 8,  i0 = iq * 2;

    float acc[2][8];
    #pragma unroll
    for (int a = 0; a < 2; ++a)
        #pragma unroll
        for (int q = 0; q < 8; ++q) acc[a][q] = 0.f;

    const int li = t & 31;
    const int lk = t >> 5;
    const int rl = r0 + li;
    const int lb = rl / NPTS, ln = rl % NPTS;

    for (int c0 = 0; c0 < NC; c0 += 32) {
        #pragma unroll
        for (int p = 0; p < 4; ++p) {
            int kk = lk + p * 8;
            Xs[kk][li] = x[((size_t)lb * NC + c0 + kk) * NPTS + ln];
        }
        #pragma unroll
        for (int jj = 0; jj < 16; ++jj) {
            int j = jj * 8 + lk;
            int c = c0 + li;
            float w;
            if (sel == 0)      w = tW1[j * NC + c];
            else if (sel == 1) w = sW1[j * (2*NC) + c];
            else               w = sW1[j * (2*NC) + NC + c];
            Ws[li][j] = w;
        }
        __syncthreads();
        #pragma unroll 8
        for (int kk = 0; kk < 32; ++kk) {
            const float2 xv = *(const float2*)&Xs[kk][i0];
            const float4 w0 = *(const float4*)&Ws[kk][j0];
            const float4 w1 = *(const float4*)&Ws[kk][j0 + 4];
            float w[8] = {w0.x,w0.y,w0.z,w0.w,w1.x,w1.y,w1.z,w1.w};
            #pragma unroll
            for (int q = 0; q < 8; ++q) {
                acc[0][q] = fmaf(xv.x, w[q], acc[0][q]);
                acc[1][q] = fmaf(xv.y, w[q], acc[1][q]);
            }
        }
        __syncthreads();
    }

    #pragma unroll
    for (int a = 0; a < 2; ++a) {
        const int r = r0 + i0 + a;
        float o[8];
        #pragma unroll
        for (int q = 0; q < 8; ++q) {
            float v = acc[a][q];
            if (sel == 0)      { v += tb1[j0+q]; v = fmaxf(v, 0.f); }
            else if (sel == 2) { v += sb1[j0+q]; }
            o[q] = v;
        }
        float* dst = (sel==0 ? T1r : (sel==1 ? P : Q)) + (size_t)r * NW + j0;
        *(float4*)dst       = make_float4(o[0],o[1],o[2],o[3]);
        *(float4*)(dst + 4) = make_float4(o[4],o[5],o[6],o[7]);
    }
}

// ---------------- Kernel B: fused pairwise-distance + per-row top-10 ----------------
// 32 rows/block, j streamed in 8 tiles of 256. Per-thread 4x8 register blocking.
// LDS union: compute tiles (Xi 36864 + Xjs 33280 + xxj 1024) vs merge buffers
// (cval 40960 + cidx 40960) -> 81920 B -> exactly 2 blocks/CU.
__global__ __launch_bounds__(256, 2) void k_topk(
    const float* __restrict__ x, const float* __restrict__ xx,
    int* __restrict__ tk)
{
    __shared__ __align__(16) char smem[81920];
    float (*Xi)[36]   = (float(*)[36])smem;             // [256][36]
    float (*Xjs)[260] = (float(*)[260])(smem + 36864);  // [32][260]
    float* xxj  = (float*)(smem + 36864 + 33280);       // [256]
    float* cval = (float*)smem;                          // [32*32*10] overlay
    int*   cidx = (int*)(smem + 40960);                  // [32*32*10] overlay

    const int t  = threadIdx.x;
    const int b  = blockIdx.x / TKTILES;
    const int i0 = (blockIdx.x % TKTILES) * 32;
    const int jq = t & 31;       // j lane
    const int iq = t >> 5;       // row quad 0..7
    const size_t xb = (size_t)b * NC * NPTS;

    // load Xi: 32 rows x 256 channels (rows >= NPTS clamped; results discarded)
    {
        const int il = t & 31;
        const int cb = (t >> 5) * 32;
        const int ri = min(i0 + il, NPTS - 1);
        #pragma unroll
        for (int p = 0; p < 32; ++p)
            Xi[cb + p][il] = x[xb + (size_t)(cb + p) * NPTS + ri];
    }

    float xxi[4];
    #pragma unroll
    for (int a = 0; a < 4; ++a)
        xxi[a] = xx[b * NPTS + min(i0 + iq*4 + a, NPTS - 1)];

    float vals[4][10]; int idxs[4][10];
    #pragma unroll
    for (int a = 0; a < 4; ++a)
        #pragma unroll
        for (int s = 0; s < 10; ++s) { vals[a][s] = -3.0e38f; idxs[a][s] = 0x7fffffff; }

    const int sqd = t & 63;      // staging quad 0..63
    const int sr4 = t >> 6;      // staging row base 0..3

    for (int jt = 0; jt < 8; ++jt) {
        const int j0 = jt * 256;
        float acc[4][8];
        #pragma unroll
        for (int a = 0; a < 4; ++a)
            #pragma unroll
            for (int q = 0; q < 8; ++q) acc[a][q] = 0.f;

        if (t < 64) {   // stage xx tile
            const int j = j0 + t*4;
            float4 v = (j + 3 < NPTS) ? *(const float4*)&xx[b*NPTS + j]
                                      : make_float4(0.f,0.f,0.f,0.f);
            *(float4*)&xxj[t*4] = v;
        }

        for (int c0 = 0; c0 < NC; c0 += 32) {
            // stage Xjs: 32 kk x 256 j (wave reads 1KB contiguous per instr)
            #pragma unroll
            for (int p = 0; p < 8; ++p) {
                const int kk = sr4 + 4*p;
                const int j  = j0 + sqd*4;
                float4 v = (j + 3 < NPTS)
                    ? *(const float4*)&x[xb + (size_t)(c0 + kk) * NPTS + j]
                    : make_float4(0.f,0.f,0.f,0.f);
                *(float4*)&Xjs[kk][sqd*4] = v;
            }
            __syncthreads();
            #pragma unroll 4
            for (int kk = 0; kk < 32; ++kk) {
                const float4 xi = *(const float4*)&Xi[c0 + kk][iq*4];
                #pragma unroll
                for (int p = 0; p < 4; ++p) {
                    const float2 xj = *(const float2*)&Xjs[kk][2*jq + 64*p];
                    acc[0][2*p]   = fmaf(xi.x, xj.x, acc[0][2*p]);
                    acc[0][2*p+1] = fmaf(xi.x, xj.y, acc[0][2*p+1]);
                    acc[1][2*p]   = fmaf(xi.y, xj.x, acc[1][2*p]);
                    acc[1][2*p+1] = fmaf(xi.y, xj.y, acc[1][2*p+1]);
                    acc[2][2*p]   = fmaf(xi.z, xj.x, acc[2][2*p]);
                    acc[2][2*p+1] = fmaf(xi.z, xj.y, acc[2][2*p+1]);
                    acc[3][2*p]   = fmaf(xi.w, xj.x, acc[3][2*p]);
                    acc[3][2*p+1] = fmaf(xi.w, xj.y, acc[3][2*p+1]);
                }
            }
            __syncthreads();
        }

        // streamed sorted-insert; per-thread j ascending -> lowest-index-on-tie
        #pragma unroll
        for (int p = 0; p < 4; ++p) {
            #pragma unroll
            for (int e = 0; e < 2; ++e) {
                const int jo = 2*jq + 64*p + e;
                const int j  = j0 + jo;
                if (j < NPTS) {
                    const float xxv = xxj[jo];
                    #pragma unroll
                    for (int a = 0; a < 4; ++a) {
                        const float d = 2.f*acc[a][2*p+e] - xxv - xxi[a];
                        if (d > vals[a][9]) {
                            float v = d; int id = j;
                            #pragma unroll
                            for (int s = 0; s < 10; ++s) {
                                if (v > vals[a][s]) {
                                    float tv = vals[a][s]; vals[a][s] = v; v = tv;
                                    int   ti = idxs[a][s]; idxs[a][s] = id; id = ti;
                                }
                            }
                        }
                    }
                }
            }
        }
        __syncthreads();   // protect xxj/Xjs before next jt staging
    }

    // dump per-thread lists (32 lists per row) into overlay buffers
    #pragma unroll
    for (int a = 0; a < 4; ++a) {
        const int base = ((iq*4 + a)*32 + jq) * 10;
        #pragma unroll
        for (int s = 0; s < 10; ++s) { cval[base+s] = vals[a][s]; cidx[base+s] = idxs[a][s]; }
    }
    __syncthreads();

    // 5-step binary pairwise merge: 32 lists -> 1 per row
#define MSTEP(S)                                                            \
    for (int w = t; w < 32*(S); w += 256) {                                 \
        const int row = w / (S), l = w % (S);                               \
        const int A = (row*32 + l) * 10;                                    \
        const int Bq = (row*32 + l + (S)) * 10;                             \
        float ov[10]; int oi[10]; int pa = 0, pb = 0;                       \
        _Pragma("unroll")                                                   \
        for (int s = 0; s < 10; ++s) {                                      \
            const float va = cval[A + pa], vb = cval[Bq + pb];              \
            const int   ia = cidx[A + pa], ib = cidx[Bq + pb];              \
            const bool ta = (va > vb) || (va == vb && ia < ib);             \
            ov[s] = ta ? va : vb; oi[s] = ta ? ia : ib;                     \
            pa += ta ? 1 : 0; pb += ta ? 0 : 1;                             \
        }                                                                   \
        _Pragma("unroll")                                                   \
        for (int s = 0; s < 10; ++s) { cval[A+s] = ov[s]; cidx[A+s] = oi[s]; } \
    }                                                                       \
    __syncthreads();

    MSTEP(16) MSTEP(8) MSTEP(4) MSTEP(2) MSTEP(1)
#undef MSTEP

    if (t < 32) {
        const int gr = i0 + t;
        if (gr < NPTS) {
            int* op = tk + (size_t)(b*NPTS + gr) * NK;
            const int A = (t*32) * 10;
            #pragma unroll
            for (int s = 0; s < NK; ++s) op[s] = b*NPTS + cidx[A+s];
        }
    }
}

// ---------------- Kernel D: fused tail (8 points/block, 2 blocks/CU) ----------------
__global__ __launch_bounds__(256, 2) void k_fused(
    const float* __restrict__ x,
    const int* __restrict__ nb, const int* __restrict__ tk,
    const float* __restrict__ T1r, const float* __restrict__ P, const float* __restrict__ Q,
    const float* __restrict__ tW2, const float* __restrict__ tb2,
    const float* __restrict__ sW2, const float* __restrict__ sb2,
    const float* __restrict__ tW3, const float* __restrict__ tb3,
    const float* __restrict__ sW3, const float* __restrict__ sb3,
    float* __restrict__ out)
{
    __shared__ float Zs[8][132];        //  4224 B
    __shared__ float G2s[80][132];      // 42240 B
    __shared__ float Wt[32][132];       // 16896 B
    __shared__ float Ws2[32][132];      // 16896 B   -> 80256 B total

    const int t  = threadIdx.x;
    const int r0 = blockIdx.x * 8;
    const int bb = r0 / NPTS;
    const int n0 = r0 % NPTS;

    // ---- phase 1: build Z and G2 ----
    {
        const int o    = t & 127;
        const int half = t >> 7;
        const int g4   = o & ~3;

        const float4 f0 = *(const float4*)&tW2[o*12];
        const float4 f1 = *(const float4*)&tW2[o*12 + 4];
        const float4 f2 = *(const float4*)&tW2[o*12 + 8];
        const float4 wt0 = make_float4(f0.x, f0.w, f1.z, f2.y);
        const float4 wt1 = make_float4(f0.y, f1.x, f1.w, f2.z);
        const float4 wt2 = make_float4(f0.z, f1.y, f2.x, f2.w);
        const float4 wsw = *(const float4*)&sW2[o*4];
        const float tb2o = tb2[o], sb2o = sb2[o];

        #pragma unroll
        for (int ptl = 0; ptl < 4; ++ptl) {
            const int pt = half*4 + ptl;
            const int r  = r0 + pt;
            // prefetch all indices, then issue all row gathers (ILP)
            const int nb0 = nb[r*3+0], nb1 = nb[r*3+1], nb2 = nb[r*3+2];
            int ki[NK];
            #pragma unroll
            for (int k = 0; k < NK; ++k) ki[k] = tk[r*NK + k];
            const float4 h0 = *(const float4*)&T1r[(size_t)nb0*NW + g4];
            const float4 h1 = *(const float4*)&T1r[(size_t)nb1*NW + g4];
            const float4 h2 = *(const float4*)&T1r[(size_t)nb2*NW + g4];
            const float4 qf = *(const float4*)&Q[(size_t)r*NW + g4];
            float4 pf[NK];
            #pragma unroll
            for (int k = 0; k < NK; ++k) pf[k] = *(const float4*)&P[(size_t)ki[k]*NW + g4];

            const float z = tb2o + dot4(wt0,h0) + dot4(wt1,h1) + dot4(wt2,h2);
            Zs[pt][o] = fmaxf(z, 0.f);
            #pragma unroll
            for (int k = 0; k < NK; ++k) {
                const float4 g1 = relu4(add4(pf[k], qf));
                G2s[pt*NK + k][o] = fmaxf(dot4(wsw, g1) + sb2o, 0.f);
            }
        }
    }
    __syncthreads();

    // ---- phase 2: 11 matvecs 128->256, max over k, residual+relu ----
    const int o2l = t >> 3;   // 0..31
    const int pth = t & 7;    // 0..7
    for (int chunk = 0; chunk < 8; ++chunk) {
        {
            const int row = t >> 3, c4 = t & 7;
            #pragma unroll
            for (int qq = 0; qq < 4; ++qq) {
                const int c = c4*16 + qq*4;
                *(float4*)&Wt[row][c]  = *(const float4*)&tW3[(size_t)(chunk*32+row)*NW + c];
                *(float4*)&Ws2[row][c] = *(const float4*)&sW3[(size_t)(chunk*32+row)*NW + c];
            }
        }
        __syncthreads();

        float res[11];
        #pragma unroll
        for (int s = 0; s < 11; ++s) res[s] = 0.f;

        #pragma unroll 2
        for (int c4 = 0; c4 < 32; ++c4) {
            const int c = c4*4;
            const float4 w3t = *(const float4*)&Wt[o2l][c];
            const float4 w3s = *(const float4*)&Ws2[o2l][c];
            const float4 z4  = *(const float4*)&Zs[pth][c];
            res[0] += dot4(w3t, z4);
            #pragma unroll
            for (int k = 0; k < NK; ++k) {
                const float4 g4v = *(const float4*)&G2s[pth*NK + k][c];
                res[1+k] += dot4(w3s, g4v);
            }
        }

        const int o2 = chunk*32 + o2l;
        float sv = res[1];
        #pragma unroll
        for (int k = 1; k < NK; ++k) sv = fmaxf(sv, res[1+k]);
        const size_t gi = ((size_t)bb * NC + o2) * NPTS + (n0 + pth);
        const float v = res[0] + tb3[o2] + sv + sb3[o2] + x[gi];
        out[gi] = fmaxf(v, 0.f);
        __syncthreads();
    }
}

extern "C" void kernel_launch(void* const* d_in, const int* in_sizes, int n_in,
                              void* d_out, int out_size, void* d_ws, size_t ws_size,
                              hipStream_t stream) {
    (void)in_sizes; (void)n_in; (void)out_size; (void)ws_size;
    const float* x   = (const float*)d_in[0];
    const int*   nb  = (const int*)d_in[2];
    const float* tW1 = (const float*)d_in[3];
    const float* tb1 = (const float*)d_in[4];
    const float* tW2 = (const float*)d_in[5];
    const float* tb2 = (const float*)d_in[6];
    const float* tW3 = (const float*)d_in[7];
    const float* tb3 = (const float*)d_in[8];
    const float* sW1 = (const float*)d_in[9];
    const float* sb1 = (const float*)d_in[10];
    const float* sW2 = (const float*)d_in[11];
    const float* sb2 = (const float*)d_in[12];
    const float* sW3 = (const float*)d_in[13];
    const float* sb3 = (const float*)d_in[14];
    float* out = (float*)d_out;

    float* ws  = (float*)d_ws;
    float* T1r = ws;
    float* P   = ws + (size_t)NROWS * NW;
    float* Q   = ws + (size_t)2 * NROWS * NW;
    float* xxp = ws + (size_t)3 * NROWS * NW;
    int*   tk  = (int*)(ws + (size_t)3 * NROWS * NW + NROWS);

    k_xx<<<(NROWS + 255) / 256, 256, 0, stream>>>(x, xxp);
    k_rowgemm<<<dim3(NROWS / 32, 3), 256, 0, stream>>>(x, tW1, tb1, sW1, sb1, T1r, P, Q);
    k_topk<<<NBATCH * TKTILES, 256, 0, stream>>>(x, xxp, tk);
    k_fused<<<NROWS / 8, 256, 0, stream>>>(x, nb, tk, T1r, P, Q,
                                           tW2, tb2, sW2, sb2, tW3, tb3, sW3, sb3, out);
}

// Round 3
// 766.191 us; speedup vs baseline: 2.3073x; 1.0783x over previous
//
#include <hip/hip_runtime.h>

#define NPTS 2000
#define NBATCH 8
#define NC 256
#define NW 128
#define NK 10
#define NROWS (NBATCH * NPTS)

typedef _Float16 f16x8 __attribute__((ext_vector_type(8)));
typedef float f32x4 __attribute__((ext_vector_type(4)));

__device__ __forceinline__ float dot4(float4 a, float4 b) {
    return a.x*b.x + a.y*b.y + a.z*b.z + a.w*b.w;
}
__device__ __forceinline__ float4 relu4(float4 a) {
    return make_float4(fmaxf(a.x,0.f), fmaxf(a.y,0.f), fmaxf(a.z,0.f), fmaxf(a.w,0.f));
}
__device__ __forceinline__ float4 add4(float4 a, float4 b) {
    return make_float4(a.x+b.x, a.y+b.y, a.z+b.z, a.w+b.w);
}

__device__ __forceinline__ void ins10(float d, int j, float* vals, int* idxs) {
    if (d > vals[9]) {
        float v = d; int id = j;
        #pragma unroll
        for (int s = 0; s < 10; ++s) {
            if (v > vals[s]) {
                float tv = vals[s]; vals[s] = v; v = tv;
                int   ti = idxs[s]; idxs[s] = id; id = ti;
            }
        }
    }
}

// ---------------- Kernel P: transpose to row-major f16 hi/lo + row norms ----------------
__global__ __launch_bounds__(256) void k_prep(
    const float* __restrict__ x, _Float16* __restrict__ xh,
    _Float16* __restrict__ xl, float* __restrict__ xx)
{
    __shared__ float T[64][259];
    __shared__ float Pp[64][4];
    const int t  = threadIdx.x;
    const int b  = blockIdx.x >> 5;
    const int n0 = (blockIdx.x & 31) * 64;

    #pragma unroll
    for (int p = 0; p < 64; ++p) {
        const int idx = p*256 + t;
        const int c = idx >> 6, nl = idx & 63;
        T[nl][c] = x[((size_t)b*NC + c)*NPTS + min(n0 + nl, NPTS-1)];
    }
    __syncthreads();

    const int row = t >> 2, q = t & 3;
    const int gr  = n0 + row;
    float ss = 0.f;
    if (gr < NPTS) {
        const size_t base = ((size_t)b*NPTS + gr)*NC + q*64;
        #pragma unroll
        for (int g8 = 0; g8 < 8; ++g8) {
            f16x8 vh, vl;
            #pragma unroll
            for (int e = 0; e < 8; ++e) {
                const float f = T[row][q*64 + g8*8 + e];
                ss = fmaf(f, f, ss);
                const _Float16 h = (_Float16)f;
                vh[e] = h;
                vl[e] = (_Float16)(f - (float)h);
            }
            *(f16x8*)&xh[base + g8*8] = vh;
            *(f16x8*)&xl[base + g8*8] = vl;
        }
    }
    Pp[row][q] = ss;
    __syncthreads();
    if (t < 64 && n0 + t < NPTS)
        xx[(size_t)b*NPTS + n0 + t] = Pp[t][0] + Pp[t][1] + Pp[t][2] + Pp[t][3];
}

// ---------------- Kernel A: row GEMM -> T1r / P / Q (unchanged) ----------------
__global__ __launch_bounds__(256) void k_rowgemm(
    const float* __restrict__ x,
    const float* __restrict__ tW1, const float* __restrict__ tb1,
    const float* __restrict__ sW1, const float* __restrict__ sb1,
    float* __restrict__ T1r, float* __restrict__ P, float* __restrict__ Q)
{
    __shared__ float Xs[32][34];
    __shared__ float Ws[32][132];
    const int t  = threadIdx.x;
    const int r0 = blockIdx.x * 32;
    const int sel = blockIdx.y;
    const int jq = t & 15,  iq = t >> 4;
    const int j0 = jq * 8,  i0 = iq * 2;

    float acc[2][8];
    #pragma unroll
    for (int a = 0; a < 2; ++a)
        #pragma unroll
        for (int q = 0; q < 8; ++q) acc[a][q] = 0.f;

    const int li = t & 31;
    const int lk = t >> 5;
    const int rl = r0 + li;
    const int lb = rl / NPTS, ln = rl % NPTS;

    for (int c0 = 0; c0 < NC; c0 += 32) {
        #pragma unroll
        for (int p = 0; p < 4; ++p) {
            int kk = lk + p * 8;
            Xs[kk][li] = x[((size_t)lb * NC + c0 + kk) * NPTS + ln];
        }
        #pragma unroll
        for (int jj = 0; jj < 16; ++jj) {
            int j = jj * 8 + lk;
            int c = c0 + li;
            float w;
            if (sel == 0)      w = tW1[j * NC + c];
            else if (sel == 1) w = sW1[j * (2*NC) + c];
            else               w = sW1[j * (2*NC) + NC + c];
            Ws[li][j] = w;
        }
        __syncthreads();
        #pragma unroll 8
        for (int kk = 0; kk < 32; ++kk) {
            const float2 xv = *(const float2*)&Xs[kk][i0];
            const float4 w0 = *(const float4*)&Ws[kk][j0];
            const float4 w1 = *(const float4*)&Ws[kk][j0 + 4];
            float w[8] = {w0.x,w0.y,w0.z,w0.w,w1.x,w1.y,w1.z,w1.w};
            #pragma unroll
            for (int q = 0; q < 8; ++q) {
                acc[0][q] = fmaf(xv.x, w[q], acc[0][q]);
                acc[1][q] = fmaf(xv.y, w[q], acc[1][q]);
            }
        }
        __syncthreads();
    }

    #pragma unroll
    for (int a = 0; a < 2; ++a) {
        const int r = r0 + i0 + a;
        float o[8];
        #pragma unroll
        for (int q = 0; q < 8; ++q) {
            float v = acc[a][q];
            if (sel == 0)      { v += tb1[j0+q]; v = fmaxf(v, 0.f); }
            else if (sel == 2) { v += sb1[j0+q]; }
            o[q] = v;
        }
        float* dst = (sel==0 ? T1r : (sel==1 ? P : Q)) + (size_t)r * NW + j0;
        *(float4*)dst       = make_float4(o[0],o[1],o[2],o[3]);
        *(float4*)(dst + 4) = make_float4(o[4],o[5],o[6],o[7]);
    }
}

// ---------------- Kernel B: MFMA f16x3-split distance GEMM + fused top-10 ----------------
// Block: 64 i-rows, full j sweep (16 iters x 128 j). 4 waves, wave tile 32i x 64j.
// A (64x256 hi/lo f16) resident in LDS; B streamed in 32-wide K chunks, double-buffered.
#define ASTR 264   // f16 row stride for A (256 + 8 pad)
#define BSTR 40    // f16 row stride for B chunk (32 + 8 pad)
#define SSTR 132   // f32 row stride for Sbuf
__global__ __launch_bounds__(256, 1) void k_topk(
    const _Float16* __restrict__ xh, const _Float16* __restrict__ xl,
    const float* __restrict__ xx, int* __restrict__ tk)
{
    __shared__ __align__(16) char smem[142336];
    _Float16* Ah  = (_Float16*)smem;                 // 64 x 264  (33792 B)
    _Float16* Al  = (_Float16*)(smem + 33792);       // 33792 B
    _Float16* Bh0 = (_Float16*)(smem + 67584);       // 2 x (128 x 40) = 2 x 10240 B
    _Float16* Bl0 = (_Float16*)(smem + 88064);
    float*    Sbuf = (float*)(smem + 108544);        // 64 x 132 f32 (33792 B)
    float*    mval = (float*)(smem + 108544);        // overlay: 64*4*10 f32
    int*      midx = (int*)(smem + 118784);          // 64*4*10 int

    const int t    = threadIdx.x;
    const int b    = blockIdx.x >> 5;
    const int i0   = (blockIdx.x & 31) * 64;
    const int lane = t & 63;
    const int w    = t >> 6;
    const int wi   = w >> 1, wj = w & 1;
    const int lr   = lane & 15, lg = lane >> 4;
    const size_t rowbase = (size_t)b * NPTS;

    // ---- stage A (hi/lo), once ----
    {
        const int row = t >> 2, q = t & 3;
        const int gr = min(i0 + row, NPTS - 1);
        const f16x8* sh = (const f16x8*)&xh[(rowbase + gr)*NC + q*64];
        const f16x8* sl = (const f16x8*)&xl[(rowbase + gr)*NC + q*64];
        f16x8* dh = (f16x8*)&Ah[row*ASTR + q*64];
        f16x8* dl = (f16x8*)&Al[row*ASTR + q*64];
        #pragma unroll
        for (int e = 0; e < 8; ++e) { dh[e] = sh[e]; dl[e] = sl[e]; }
    }

    float vals[10]; int idxs[10];
    #pragma unroll
    for (int s = 0; s < 10; ++s) { vals[s] = -3.0e38f; idxs[s] = 0x7fffffff; }

    const int sj = t >> 1, sq = t & 1;   // B staging: j-row, c-half

    // ---- preload chunk 0 of jt 0 into buf 0 ----
    {
        const int jg = min(sj, NPTS - 1);
        const f16x8* sh = (const f16x8*)&xh[(rowbase + jg)*NC + sq*16];
        const f16x8* sl = (const f16x8*)&xl[(rowbase + jg)*NC + sq*16];
        f16x8 h0 = sh[0], h1 = sh[1], l0 = sl[0], l1 = sl[1];
        *(f16x8*)&Bh0[sj*BSTR + sq*16]     = h0;
        *(f16x8*)&Bh0[sj*BSTR + sq*16 + 8] = h1;
        *(f16x8*)&Bl0[sj*BSTR + sq*16]     = l0;
        *(f16x8*)&Bl0[sj*BSTR + sq*16 + 8] = l1;
    }

    for (int jt = 0; jt < 16; ++jt) {
        f32x4 acc[2][4] = {};
        for (int c = 0; c < 8; ++c) {
            __syncthreads();   // buf[c&1] ready; everyone done reading buf[(c+1)&1]

            // issue next-chunk global loads (hidden under MFMA below)
            const int ci = jt*8 + c + 1;
            const bool hasnext = (ci < 128);
            f16x8 nh0, nh1, nl0, nl1;
            if (hasnext) {
                const int njt = ci >> 3, ncc = ci & 7;
                const int jg = min(njt*128 + sj, NPTS - 1);
                const f16x8* sh = (const f16x8*)&xh[(rowbase + jg)*NC + ncc*32 + sq*16];
                const f16x8* sl = (const f16x8*)&xl[(rowbase + jg)*NC + ncc*32 + sq*16];
                nh0 = sh[0]; nh1 = sh[1]; nl0 = sl[0]; nl1 = sl[1];
            }

            // ---- 24 MFMA on buf[c&1] ----
            {
                _Float16* Bh = Bh0 + (c & 1)*5120;
                _Float16* Bl = Bl0 + (c & 1)*5120;
                const int ko = c*32 + lg*8;
                const f16x8 a0h = *(const f16x8*)&Ah[(wi*32 +      lr)*ASTR + ko];
                const f16x8 a1h = *(const f16x8*)&Ah[(wi*32 + 16 + lr)*ASTR + ko];
                const f16x8 a0l = *(const f16x8*)&Al[(wi*32 +      lr)*ASTR + ko];
                const f16x8 a1l = *(const f16x8*)&Al[(wi*32 + 16 + lr)*ASTR + ko];
                #pragma unroll
                for (int n = 0; n < 4; ++n) {
                    const f16x8 bh = *(const f16x8*)&Bh[(wj*64 + n*16 + lr)*BSTR + lg*8];
                    const f16x8 bl = *(const f16x8*)&Bl[(wj*64 + n*16 + lr)*BSTR + lg*8];
                    acc[0][n] = __builtin_amdgcn_mfma_f32_16x16x32_f16(a0h, bh, acc[0][n], 0,0,0);
                    acc[0][n] = __builtin_amdgcn_mfma_f32_16x16x32_f16(a0h, bl, acc[0][n], 0,0,0);
                    acc[0][n] = __builtin_amdgcn_mfma_f32_16x16x32_f16(a0l, bh, acc[0][n], 0,0,0);
                    acc[1][n] = __builtin_amdgcn_mfma_f32_16x16x32_f16(a1h, bh, acc[1][n], 0,0,0);
                    acc[1][n] = __builtin_amdgcn_mfma_f32_16x16x32_f16(a1h, bl, acc[1][n], 0,0,0);
                    acc[1][n] = __builtin_amdgcn_mfma_f32_16x16x32_f16(a1l, bh, acc[1][n], 0,0,0);
                }
            }

            // write next chunk into buf[(c+1)&1]
            if (hasnext) {
                _Float16* Bh = Bh0 + ((c+1) & 1)*5120;
                _Float16* Bl = Bl0 + ((c+1) & 1)*5120;
                *(f16x8*)&Bh[sj*BSTR + sq*16]     = nh0;
                *(f16x8*)&Bh[sj*BSTR + sq*16 + 8] = nh1;
                *(f16x8*)&Bl[sj*BSTR + sq*16]     = nl0;
                *(f16x8*)&Bl[sj*BSTR + sq*16 + 8] = nl1;
            }
        }

        // ---- epilogue: dump inner products, then streamed top-10 update ----
        #pragma unroll
        for (int m = 0; m < 2; ++m) {
            #pragma unroll
            for (int n = 0; n < 4; ++n) {
                const int rb = wi*32 + m*16 + lg*4;
                const int cl = wj*64 + n*16 + lr;
                #pragma unroll
                for (int q = 0; q < 4; ++q)
                    Sbuf[(rb + q)*SSTR + cl] = acc[m][n][q];
            }
        }
        __syncthreads();
        {
            const int row = t & 63, jc = t >> 6;
            const float* srow = &Sbuf[row*SSTR + jc*32];
            const int jb = jt*128 + jc*32;
            #pragma unroll
            for (int q4 = 0; q4 < 8; ++q4) {
                const int jg = jb + q4*4;
                if (jg < NPTS) {
                    const f32x4 sv = *(const f32x4*)&srow[q4*4];
                    if (jg + 3 < NPTS) {
                        const f32x4 xv = *(const f32x4*)&xx[rowbase + jg];
                        #pragma unroll
                        for (int e = 0; e < 4; ++e)
                            ins10(2.f*sv[e] - xv[e], jg + e, vals, idxs);
                    } else {
                        #pragma unroll
                        for (int e = 0; e < 4; ++e)
                            if (jg + e < NPTS)
                                ins10(2.f*sv[e] - xx[rowbase + jg + e], jg + e, vals, idxs);
                    }
                }
            }
        }
        // next iteration's chunk-0 barrier orders selection reads vs future Sbuf writes
    }

    __syncthreads();
    // dump per-thread lists (4 per row) into merge area
    {
        const int row = t & 63, jc = t >> 6;
        float* mv = &mval[(row*4 + jc)*10];
        int*   mi = &midx[(row*4 + jc)*10];
        #pragma unroll
        for (int s = 0; s < 10; ++s) { mv[s] = vals[s]; mi[s] = idxs[s]; }
    }
    __syncthreads();
    // merge step 1: (l, l+2) -> l for l in {0,1}
    if (t < 128) {
        const int row = t >> 1, l = t & 1;
        float* va = &mval[(row*4 + l)*10];     int* ia = &midx[(row*4 + l)*10];
        const float* vb = &mval[(row*4 + l + 2)*10]; const int* ib = &midx[(row*4 + l + 2)*10];
        float ov[10]; int oi[10]; int pa = 0, pb = 0;
        #pragma unroll
        for (int s = 0; s < 10; ++s) {
            const float A = va[pa], Bv = vb[pb];
            const int  Ai = ia[pa], Bi = ib[pb];
            const bool ta = (A > Bv) || (A == Bv && Ai < Bi);
            ov[s] = ta ? A : Bv; oi[s] = ta ? Ai : Bi;
            pa += ta ? 1 : 0; pb += ta ? 0 : 1;
        }
        #pragma unroll
        for (int s = 0; s < 10; ++s) { va[s] = ov[s]; ia[s] = oi[s]; }
    }
    __syncthreads();
    // merge step 2 + output
    if (t < 64) {
        const int gi = i0 + t;
        if (gi < NPTS) {
            const float* va = &mval[(t*4 + 0)*10]; const int* ia = &midx[(t*4 + 0)*10];
            const float* vb = &mval[(t*4 + 1)*10]; const int* ib = &midx[(t*4 + 1)*10];
            int* op = &tk[(size_t)(b*NPTS + gi)*NK];
            int pa = 0, pb = 0;
            #pragma unroll
            for (int s = 0; s < 10; ++s) {
                const float A = va[pa], Bv = vb[pb];
                const int  Ai = ia[pa], Bi = ib[pb];
                const bool ta = (A > Bv) || (A == Bv && Ai < Bi);
                op[s] = b*NPTS + (ta ? Ai : Bi);
                pa += ta ? 1 : 0; pb += ta ? 0 : 1;
            }
        }
    }
}

// ---------------- Kernel D: fused tail (unchanged) ----------------
__global__ __launch_bounds__(256, 2) void k_fused(
    const float* __restrict__ x,
    const int* __restrict__ nb, const int* __restrict__ tk,
    const float* __restrict__ T1r, const float* __restrict__ P, const float* __restrict__ Q,
    const float* __restrict__ tW2, const float* __restrict__ tb2,
    const float* __restrict__ sW2, const float* __restrict__ sb2,
    const float* __restrict__ tW3, const float* __restrict__ tb3,
    const float* __restrict__ sW3, const float* __restrict__ sb3,
    float* __restrict__ out)
{
    __shared__ float Zs[8][132];
    __shared__ float G2s[80][132];
    __shared__ float Wt[32][132];
    __shared__ float Ws2[32][132];

    const int t  = threadIdx.x;
    const int r0 = blockIdx.x * 8;
    const int bb = r0 / NPTS;
    const int n0 = r0 % NPTS;

    {
        const int o    = t & 127;
        const int half = t >> 7;
        const int g4   = o & ~3;

        const float4 f0 = *(const float4*)&tW2[o*12];
        const float4 f1 = *(const float4*)&tW2[o*12 + 4];
        const float4 f2 = *(const float4*)&tW2[o*12 + 8];
        const float4 wt0 = make_float4(f0.x, f0.w, f1.z, f2.y);
        const float4 wt1 = make_float4(f0.y, f1.x, f1.w, f2.z);
        const float4 wt2 = make_float4(f0.z, f1.y, f2.x, f2.w);
        const float4 wsw = *(const float4*)&sW2[o*4];
        const float tb2o = tb2[o], sb2o = sb2[o];

        #pragma unroll
        for (int ptl = 0; ptl < 4; ++ptl) {
            const int pt = half*4 + ptl;
            const int r  = r0 + pt;
            const int nb0 = nb[r*3+0], nb1 = nb[r*3+1], nb2 = nb[r*3+2];
            int ki[NK];
            #pragma unroll
            for (int k = 0; k < NK; ++k) ki[k] = tk[r*NK + k];
            const float4 h0 = *(const float4*)&T1r[(size_t)nb0*NW + g4];
            const float4 h1 = *(const float4*)&T1r[(size_t)nb1*NW + g4];
            const float4 h2 = *(const float4*)&T1r[(size_t)nb2*NW + g4];
            const float4 qf = *(const float4*)&Q[(size_t)r*NW + g4];
            float4 pf[NK];
            #pragma unroll
            for (int k = 0; k < NK; ++k) pf[k] = *(const float4*)&P[(size_t)ki[k]*NW + g4];

            const float z = tb2o + dot4(wt0,h0) + dot4(wt1,h1) + dot4(wt2,h2);
            Zs[pt][o] = fmaxf(z, 0.f);
            #pragma unroll
            for (int k = 0; k < NK; ++k) {
                const float4 g1 = relu4(add4(pf[k], qf));
                G2s[pt*NK + k][o] = fmaxf(dot4(wsw, g1) + sb2o, 0.f);
            }
        }
    }
    __syncthreads();

    const int o2l = t >> 3;
    const int pth = t & 7;
    for (int chunk = 0; chunk < 8; ++chunk) {
        {
            const int row = t >> 3, c4 = t & 7;
            #pragma unroll
            for (int qq = 0; qq < 4; ++qq) {
                const int c = c4*16 + qq*4;
                *(float4*)&Wt[row][c]  = *(const float4*)&tW3[(size_t)(chunk*32+row)*NW + c];
                *(float4*)&Ws2[row][c] = *(const float4*)&sW3[(size_t)(chunk*32+row)*NW + c];
            }
        }
        __syncthreads();

        float res[11];
        #pragma unroll
        for (int s = 0; s < 11; ++s) res[s] = 0.f;

        #pragma unroll 2
        for (int c4 = 0; c4 < 32; ++c4) {
            const int c = c4*4;
            const float4 w3t = *(const float4*)&Wt[o2l][c];
            const float4 w3s = *(const float4*)&Ws2[o2l][c];
            const float4 z4  = *(const float4*)&Zs[pth][c];
            res[0] += dot4(w3t, z4);
            #pragma unroll
            for (int k = 0; k < NK; ++k) {
                const float4 g4v = *(const float4*)&G2s[pth*NK + k][c];
                res[1+k] += dot4(w3s, g4v);
            }
        }

        const int o2 = chunk*32 + o2l;
        float sv = res[1];
        #pragma unroll
        for (int k = 1; k < NK; ++k) sv = fmaxf(sv, res[1+k]);
        const size_t gi = ((size_t)bb * NC + o2) * NPTS + (n0 + pth);
        const float v = res[0] + tb3[o2] + sv + sb3[o2] + x[gi];
        out[gi] = fmaxf(v, 0.f);
        __syncthreads();
    }
}

extern "C" void kernel_launch(void* const* d_in, const int* in_sizes, int n_in,
                              void* d_out, int out_size, void* d_ws, size_t ws_size,
                              hipStream_t stream) {
    (void)in_sizes; (void)n_in; (void)out_size; (void)ws_size;
    const float* x   = (const float*)d_in[0];
    const int*   nb  = (const int*)d_in[2];
    const float* tW1 = (const float*)d_in[3];
    const float* tb1 = (const float*)d_in[4];
    const float* tW2 = (const float*)d_in[5];
    const float* tb2 = (const float*)d_in[6];
    const float* tW3 = (const float*)d_in[7];
    const float* tb3 = (const float*)d_in[8];
    const float* sW1 = (const float*)d_in[9];
    const float* sb1 = (const float*)d_in[10];
    const float* sW2 = (const float*)d_in[11];
    const float* sb2 = (const float*)d_in[12];
    const float* sW3 = (const float*)d_in[13];
    const float* sb3 = (const float*)d_in[14];
    float* out = (float*)d_out;

    float* ws  = (float*)d_ws;
    float* T1r = ws;                                   // 16000*128 f32
    float* P   = ws + (size_t)NROWS * NW;              // 16000*128 f32
    float* Q   = ws + (size_t)2 * NROWS * NW;          // 16000*128 f32
    float* xxp = ws + (size_t)3 * NROWS * NW;          // 16000 f32
    int*   tk  = (int*)(ws + (size_t)3 * NROWS * NW + NROWS);          // 16000*10 int
    _Float16* xh = (_Float16*)(ws + (size_t)3 * NROWS * NW + NROWS + NROWS*NK/1 + 0) ;
    // recompute cleanly in bytes:
    {
        size_t off_f = (size_t)3 * NROWS * NW + NROWS + (size_t)NROWS * NK; // floats+ints consumed
        xh = (_Float16*)((char*)d_ws + off_f * 4);
    }
    _Float16* xl = xh + (size_t)NROWS * NC;            // 16000*256 f16 each

    k_prep<<<NBATCH * 32, 256, 0, stream>>>(x, xh, xl, xxp);
    k_rowgemm<<<dim3(NROWS / 32, 3), 256, 0, stream>>>(x, tW1, tb1, sW1, sb1, T1r, P, Q);
    k_topk<<<NBATCH * 32, 256, 0, stream>>>(xh, xl, xxp, tk);
    k_fused<<<NROWS / 8, 256, 0, stream>>>(x, nb, tk, T1r, P, Q,
                                           tW2, tb2, sW2, sb2, tW3, tb3, sW3, sb3, out);
}

// Round 4
// 515.652 us; speedup vs baseline: 3.4284x; 1.4859x over previous
//
#include <hip/hip_runtime.h>

#define NPTS 2000
#define NBATCH 8
#define NC 256
#define NW 128
#define NK 10
#define NROWS (NBATCH * NPTS)

typedef _Float16 f16x8 __attribute__((ext_vector_type(8)));
typedef _Float16 f16x4 __attribute__((ext_vector_type(4)));
typedef float f32x4 __attribute__((ext_vector_type(4)));

__device__ __forceinline__ float dot4(float4 a, float4 b) {
    return a.x*b.x + a.y*b.y + a.z*b.z + a.w*b.w;
}
__device__ __forceinline__ float4 relu4(float4 a) {
    return make_float4(fmaxf(a.x,0.f), fmaxf(a.y,0.f), fmaxf(a.z,0.f), fmaxf(a.w,0.f));
}
__device__ __forceinline__ float4 add4(float4 a, float4 b) {
    return make_float4(a.x+b.x, a.y+b.y, a.z+b.z, a.w+b.w);
}

__device__ __forceinline__ void ins10(float d, int j, float* vals, int* idxs) {
    if (d > vals[9]) {
        float v = d; int id = j;
        #pragma unroll
        for (int s = 0; s < 10; ++s) {
            if (v > vals[s]) {
                float tv = vals[s]; vals[s] = v; v = tv;
                int   ti = idxs[s]; idxs[s] = id; id = ti;
            }
        }
    }
}

// ---------------- Kernel P: transpose to row-major f16 hi/lo + row norms ----------------
__global__ __launch_bounds__(256) void k_prep(
    const float* __restrict__ x, _Float16* __restrict__ xh,
    _Float16* __restrict__ xl, float* __restrict__ xx)
{
    __shared__ float T[64][259];
    __shared__ float Pp[64][4];
    const int t  = threadIdx.x;
    const int b  = blockIdx.x >> 5;
    const int n0 = (blockIdx.x & 31) * 64;

    #pragma unroll
    for (int p = 0; p < 64; ++p) {
        const int idx = p*256 + t;
        const int c = idx >> 6, nl = idx & 63;
        T[nl][c] = x[((size_t)b*NC + c)*NPTS + min(n0 + nl, NPTS-1)];
    }
    __syncthreads();

    const int row = t >> 2, q = t & 3;
    const int gr  = n0 + row;
    float ss = 0.f;
    if (gr < NPTS) {
        const size_t base = ((size_t)b*NPTS + gr)*NC + q*64;
        #pragma unroll
        for (int g8 = 0; g8 < 8; ++g8) {
            f16x8 vh, vl;
            #pragma unroll
            for (int e = 0; e < 8; ++e) {
                const float f = T[row][q*64 + g8*8 + e];
                ss = fmaf(f, f, ss);
                const _Float16 h = (_Float16)f;
                vh[e] = h;
                vl[e] = (_Float16)(f - (float)h);
            }
            *(f16x8*)&xh[base + g8*8] = vh;
            *(f16x8*)&xl[base + g8*8] = vl;
        }
    }
    Pp[row][q] = ss;
    __syncthreads();
    if (t < 64 && n0 + t < NPTS)
        xx[(size_t)b*NPTS + n0 + t] = Pp[t][0] + Pp[t][1] + Pp[t][2] + Pp[t][3];
}

// ---------------- Kernel W: f32 -> f16 weight conversion ----------------
__global__ __launch_bounds__(256) void k_wprep(const float* __restrict__ a,
                                               _Float16* __restrict__ o, int n)
{
    const int i = (blockIdx.x*256 + threadIdx.x)*4;
    if (i < n) {
        const float4 v = *(const float4*)&a[i];
        f16x4 h = {(_Float16)v.x, (_Float16)v.y, (_Float16)v.z, (_Float16)v.w};
        *(f16x4*)&o[i] = h;
    }
}

// ---------------- Kernel A: row GEMM -> T1r / P / Q (unchanged) ----------------
__global__ __launch_bounds__(256) void k_rowgemm(
    const float* __restrict__ x,
    const float* __restrict__ tW1, const float* __restrict__ tb1,
    const float* __restrict__ sW1, const float* __restrict__ sb1,
    float* __restrict__ T1r, float* __restrict__ P, float* __restrict__ Q)
{
    __shared__ float Xs[32][34];
    __shared__ float Ws[32][132];
    const int t  = threadIdx.x;
    const int r0 = blockIdx.x * 32;
    const int sel = blockIdx.y;
    const int jq = t & 15,  iq = t >> 4;
    const int j0 = jq * 8,  i0 = iq * 2;

    float acc[2][8];
    #pragma unroll
    for (int a = 0; a < 2; ++a)
        #pragma unroll
        for (int q = 0; q < 8; ++q) acc[a][q] = 0.f;

    const int li = t & 31;
    const int lk = t >> 5;
    const int rl = r0 + li;
    const int lb = rl / NPTS, ln = rl % NPTS;

    for (int c0 = 0; c0 < NC; c0 += 32) {
        #pragma unroll
        for (int p = 0; p < 4; ++p) {
            int kk = lk + p * 8;
            Xs[kk][li] = x[((size_t)lb * NC + c0 + kk) * NPTS + ln];
        }
        #pragma unroll
        for (int jj = 0; jj < 16; ++jj) {
            int j = jj * 8 + lk;
            int c = c0 + li;
            float w;
            if (sel == 0)      w = tW1[j * NC + c];
            else if (sel == 1) w = sW1[j * (2*NC) + c];
            else               w = sW1[j * (2*NC) + NC + c];
            Ws[li][j] = w;
        }
        __syncthreads();
        #pragma unroll 8
        for (int kk = 0; kk < 32; ++kk) {
            const float2 xv = *(const float2*)&Xs[kk][i0];
            const float4 w0 = *(const float4*)&Ws[kk][j0];
            const float4 w1 = *(const float4*)&Ws[kk][j0 + 4];
            float w[8] = {w0.x,w0.y,w0.z,w0.w,w1.x,w1.y,w1.z,w1.w};
            #pragma unroll
            for (int q = 0; q < 8; ++q) {
                acc[0][q] = fmaf(xv.x, w[q], acc[0][q]);
                acc[1][q] = fmaf(xv.y, w[q], acc[1][q]);
            }
        }
        __syncthreads();
    }

    #pragma unroll
    for (int a = 0; a < 2; ++a) {
        const int r = r0 + i0 + a;
        float o[8];
        #pragma unroll
        for (int q = 0; q < 8; ++q) {
            float v = acc[a][q];
            if (sel == 0)      { v += tb1[j0+q]; v = fmaxf(v, 0.f); }
            else if (sel == 2) { v += sb1[j0+q]; }
            o[q] = v;
        }
        float* dst = (sel==0 ? T1r : (sel==1 ? P : Q)) + (size_t)r * NW + j0;
        *(float4*)dst       = make_float4(o[0],o[1],o[2],o[3]);
        *(float4*)(dst + 4) = make_float4(o[4],o[5],o[6],o[7]);
    }
}

// ---------------- Kernel B: MFMA f16x3-split distance GEMM + fused top-10 (unchanged) ----------------
#define ASTR 264
#define BSTR 40
#define SSTR 132
__global__ __launch_bounds__(256, 1) void k_topk(
    const _Float16* __restrict__ xh, const _Float16* __restrict__ xl,
    const float* __restrict__ xx, int* __restrict__ tk)
{
    __shared__ __align__(16) char smem[142336];
    _Float16* Ah  = (_Float16*)smem;
    _Float16* Al  = (_Float16*)(smem + 33792);
    _Float16* Bh0 = (_Float16*)(smem + 67584);
    _Float16* Bl0 = (_Float16*)(smem + 88064);
    float*    Sbuf = (float*)(smem + 108544);
    float*    mval = (float*)(smem + 108544);
    int*      midx = (int*)(smem + 118784);

    const int t    = threadIdx.x;
    const int b    = blockIdx.x >> 5;
    const int i0   = (blockIdx.x & 31) * 64;
    const int lane = t & 63;
    const int w    = t >> 6;
    const int wi   = w >> 1, wj = w & 1;
    const int lr   = lane & 15, lg = lane >> 4;
    const size_t rowbase = (size_t)b * NPTS;

    {
        const int row = t >> 2, q = t & 3;
        const int gr = min(i0 + row, NPTS - 1);
        const f16x8* sh = (const f16x8*)&xh[(rowbase + gr)*NC + q*64];
        const f16x8* sl = (const f16x8*)&xl[(rowbase + gr)*NC + q*64];
        f16x8* dh = (f16x8*)&Ah[row*ASTR + q*64];
        f16x8* dl = (f16x8*)&Al[row*ASTR + q*64];
        #pragma unroll
        for (int e = 0; e < 8; ++e) { dh[e] = sh[e]; dl[e] = sl[e]; }
    }

    float vals[10]; int idxs[10];
    #pragma unroll
    for (int s = 0; s < 10; ++s) { vals[s] = -3.0e38f; idxs[s] = 0x7fffffff; }

    const int sj = t >> 1, sq = t & 1;

    {
        const int jg = min(sj, NPTS - 1);
        const f16x8* sh = (const f16x8*)&xh[(rowbase + jg)*NC + sq*16];
        const f16x8* sl = (const f16x8*)&xl[(rowbase + jg)*NC + sq*16];
        f16x8 h0 = sh[0], h1 = sh[1], l0 = sl[0], l1 = sl[1];
        *(f16x8*)&Bh0[sj*BSTR + sq*16]     = h0;
        *(f16x8*)&Bh0[sj*BSTR + sq*16 + 8] = h1;
        *(f16x8*)&Bl0[sj*BSTR + sq*16]     = l0;
        *(f16x8*)&Bl0[sj*BSTR + sq*16 + 8] = l1;
    }

    for (int jt = 0; jt < 16; ++jt) {
        f32x4 acc[2][4] = {};
        for (int c = 0; c < 8; ++c) {
            __syncthreads();

            const int ci = jt*8 + c + 1;
            const bool hasnext = (ci < 128);
            f16x8 nh0, nh1, nl0, nl1;
            if (hasnext) {
                const int njt = ci >> 3, ncc = ci & 7;
                const int jg = min(njt*128 + sj, NPTS - 1);
                const f16x8* sh = (const f16x8*)&xh[(rowbase + jg)*NC + ncc*32 + sq*16];
                const f16x8* sl = (const f16x8*)&xl[(rowbase + jg)*NC + ncc*32 + sq*16];
                nh0 = sh[0]; nh1 = sh[1]; nl0 = sl[0]; nl1 = sl[1];
            }

            {
                _Float16* Bh = Bh0 + (c & 1)*5120;
                _Float16* Bl = Bl0 + (c & 1)*5120;
                const int ko = c*32 + lg*8;
                const f16x8 a0h = *(const f16x8*)&Ah[(wi*32 +      lr)*ASTR + ko];
                const f16x8 a1h = *(const f16x8*)&Ah[(wi*32 + 16 + lr)*ASTR + ko];
                const f16x8 a0l = *(const f16x8*)&Al[(wi*32 +      lr)*ASTR + ko];
                const f16x8 a1l = *(const f16x8*)&Al[(wi*32 + 16 + lr)*ASTR + ko];
                #pragma unroll
                for (int n = 0; n < 4; ++n) {
                    const f16x8 bh = *(const f16x8*)&Bh[(wj*64 + n*16 + lr)*BSTR + lg*8];
                    const f16x8 bl = *(const f16x8*)&Bl[(wj*64 + n*16 + lr)*BSTR + lg*8];
                    acc[0][n] = __builtin_amdgcn_mfma_f32_16x16x32_f16(a0h, bh, acc[0][n], 0,0,0);
                    acc[0][n] = __builtin_amdgcn_mfma_f32_16x16x32_f16(a0h, bl, acc[0][n], 0,0,0);
                    acc[0][n] = __builtin_amdgcn_mfma_f32_16x16x32_f16(a0l, bh, acc[0][n], 0,0,0);
                    acc[1][n] = __builtin_amdgcn_mfma_f32_16x16x32_f16(a1h, bh, acc[1][n], 0,0,0);
                    acc[1][n] = __builtin_amdgcn_mfma_f32_16x16x32_f16(a1h, bl, acc[1][n], 0,0,0);
                    acc[1][n] = __builtin_amdgcn_mfma_f32_16x16x32_f16(a1l, bh, acc[1][n], 0,0,0);
                }
            }

            if (hasnext) {
                _Float16* Bh = Bh0 + ((c+1) & 1)*5120;
                _Float16* Bl = Bl0 + ((c+1) & 1)*5120;
                *(f16x8*)&Bh[sj*BSTR + sq*16]     = nh0;
                *(f16x8*)&Bh[sj*BSTR + sq*16 + 8] = nh1;
                *(f16x8*)&Bl[sj*BSTR + sq*16]     = nl0;
                *(f16x8*)&Bl[sj*BSTR + sq*16 + 8] = nl1;
            }
        }

        #pragma unroll
        for (int m = 0; m < 2; ++m) {
            #pragma unroll
            for (int n = 0; n < 4; ++n) {
                const int rb = wi*32 + m*16 + lg*4;
                const int cl = wj*64 + n*16 + lr;
                #pragma unroll
                for (int q = 0; q < 4; ++q)
                    Sbuf[(rb + q)*SSTR + cl] = acc[m][n][q];
            }
        }
        __syncthreads();
        {
            const int row = t & 63, jc = t >> 6;
            const float* srow = &Sbuf[row*SSTR + jc*32];
            const int jb = jt*128 + jc*32;
            #pragma unroll
            for (int q4 = 0; q4 < 8; ++q4) {
                const int jg = jb + q4*4;
                if (jg < NPTS) {
                    const f32x4 sv = *(const f32x4*)&srow[q4*4];
                    if (jg + 3 < NPTS) {
                        const f32x4 xv = *(const f32x4*)&xx[rowbase + jg];
                        #pragma unroll
                        for (int e = 0; e < 4; ++e)
                            ins10(2.f*sv[e] - xv[e], jg + e, vals, idxs);
                    } else {
                        #pragma unroll
                        for (int e = 0; e < 4; ++e)
                            if (jg + e < NPTS)
                                ins10(2.f*sv[e] - xx[rowbase + jg + e], jg + e, vals, idxs);
                    }
                }
            }
        }
    }

    __syncthreads();
    {
        const int row = t & 63, jc = t >> 6;
        float* mv = &mval[(row*4 + jc)*10];
        int*   mi = &midx[(row*4 + jc)*10];
        #pragma unroll
        for (int s = 0; s < 10; ++s) { mv[s] = vals[s]; mi[s] = idxs[s]; }
    }
    __syncthreads();
    if (t < 128) {
        const int row = t >> 1, l = t & 1;
        float* va = &mval[(row*4 + l)*10];     int* ia = &midx[(row*4 + l)*10];
        const float* vb = &mval[(row*4 + l + 2)*10]; const int* ib = &midx[(row*4 + l + 2)*10];
        float ov[10]; int oi[10]; int pa = 0, pb = 0;
        #pragma unroll
        for (int s = 0; s < 10; ++s) {
            const float A = va[pa], Bv = vb[pb];
            const int  Ai = ia[pa], Bi = ib[pb];
            const bool ta = (A > Bv) || (A == Bv && Ai < Bi);
            ov[s] = ta ? A : Bv; oi[s] = ta ? Ai : Bi;
            pa += ta ? 1 : 0; pb += ta ? 0 : 1;
        }
        #pragma unroll
        for (int s = 0; s < 10; ++s) { va[s] = ov[s]; ia[s] = oi[s]; }
    }
    __syncthreads();
    if (t < 64) {
        const int gi = i0 + t;
        if (gi < NPTS) {
            const float* va = &mval[(t*4 + 0)*10]; const int* ia = &midx[(t*4 + 0)*10];
            const float* vb = &mval[(t*4 + 1)*10]; const int* ib = &midx[(t*4 + 1)*10];
            int* op = &tk[(size_t)(b*NPTS + gi)*NK];
            int pa = 0, pb = 0;
            #pragma unroll
            for (int s = 0; s < 10; ++s) {
                const float A = va[pa], Bv = vb[pb];
                const int  Ai = ia[pa], Bi = ib[pb];
                const bool ta = (A > Bv) || (A == Bv && Ai < Bi);
                op[s] = b*NPTS + (ta ? Ai : Bi);
                pa += ta ? 1 : 0; pb += ta ? 0 : 1;
            }
        }
    }
}

// ---------------- Kernel D: fused tail v2 — MFMA phase 2 ----------------
// 8 points/block. A (f16, LDS): rows 16p+k = G2 (k<10; 10..15 zero-pad),
// rows 128+p = Z (136..143 pad). B = f16 W3 from global (L2-resident).
// Wave w owns output channels [64w, 64w+64). Per-point m-tile -> k-max via
// reg-max + shfl_xor(16/32). Epilogue: bias + residual + relu.
#define AST 136   // f16 row stride
__global__ __launch_bounds__(256, 2) void k_fused(
    const float* __restrict__ x,
    const int* __restrict__ nb, const int* __restrict__ tk,
    const float* __restrict__ T1r, const float* __restrict__ P, const float* __restrict__ Q,
    const float* __restrict__ tW2, const float* __restrict__ tb2,
    const float* __restrict__ sW2, const float* __restrict__ sb2,
    const _Float16* __restrict__ wt3h, const _Float16* __restrict__ ws3h,
    const float* __restrict__ tb3, const float* __restrict__ sb3,
    float* __restrict__ out)
{
    __shared__ __align__(16) _Float16 A16[144*AST];   // 39168 B
    __shared__ float Ssm[8][260];                      //  8320 B
    __shared__ float Zr[8][260];                       //  8320 B

    const int t  = threadIdx.x;
    const int r0 = blockIdx.x * 8;
    const int bb = r0 / NPTS;
    const int n0 = r0 % NPTS;

    // zero A (pad rows must be 0 so pad C-rows don't pollute the k-max mask path)
    {
        const float4 z4 = make_float4(0.f,0.f,0.f,0.f);
        float4* p4 = (float4*)A16;
        #pragma unroll
        for (int i = 0; i < 10; ++i) {
            const int idx = t + i*256;
            if (idx < 2448) p4[idx] = z4;
        }
    }
    __syncthreads();

    // ---- phase 1: build G2 (f16) and Z (f16) ----
    {
        const int o    = t & 127;
        const int half = t >> 7;
        const int g4   = o & ~3;

        const float4 f0 = *(const float4*)&tW2[o*12];
        const float4 f1 = *(const float4*)&tW2[o*12 + 4];
        const float4 f2 = *(const float4*)&tW2[o*12 + 8];
        const float4 wt0 = make_float4(f0.x, f0.w, f1.z, f2.y);
        const float4 wt1 = make_float4(f0.y, f1.x, f1.w, f2.z);
        const float4 wt2 = make_float4(f0.z, f1.y, f2.x, f2.w);
        const float4 wsw = *(const float4*)&sW2[o*4];
        const float tb2o = tb2[o], sb2o = sb2[o];

        #pragma unroll
        for (int ptl = 0; ptl < 4; ++ptl) {
            const int pt = half*4 + ptl;
            const int r  = r0 + pt;
            const int nb0 = nb[r*3+0], nb1 = nb[r*3+1], nb2 = nb[r*3+2];
            int ki[NK];
            #pragma unroll
            for (int k = 0; k < NK; ++k) ki[k] = tk[r*NK + k];
            const float4 h0 = *(const float4*)&T1r[(size_t)nb0*NW + g4];
            const float4 h1 = *(const float4*)&T1r[(size_t)nb1*NW + g4];
            const float4 h2 = *(const float4*)&T1r[(size_t)nb2*NW + g4];
            const float4 qf = *(const float4*)&Q[(size_t)r*NW + g4];
            float4 pf[NK];
            #pragma unroll
            for (int k = 0; k < NK; ++k) pf[k] = *(const float4*)&P[(size_t)ki[k]*NW + g4];

            const float z = tb2o + dot4(wt0,h0) + dot4(wt1,h1) + dot4(wt2,h2);
            A16[(128 + pt)*AST + o] = (_Float16)fmaxf(z, 0.f);
            #pragma unroll
            for (int k = 0; k < NK; ++k) {
                const float4 g1 = relu4(add4(pf[k], qf));
                A16[(pt*16 + k)*AST + o] = (_Float16)fmaxf(dot4(wsw, g1) + sb2o, 0.f);
            }
        }
    }
    __syncthreads();

    // ---- phase 2: MFMA GEMM. A(144x128) x B(128 x 64-per-wave), 2 B-matrices ----
    const int lane = t & 63, w = t >> 6;
    const int lr = lane & 15, lg = lane >> 4;
    const int n0w = w * 64;

    f32x4 accG[8][4] = {};
    f32x4 accZ[4] = {};

    #pragma unroll
    for (int kt = 0; kt < 4; ++kt) {
        const int ko = kt*32 + lg*8;
        f16x8 bs[4], bt[4];
        #pragma unroll
        for (int nt = 0; nt < 4; ++nt) {
            const int n = n0w + nt*16 + lr;
            bs[nt] = *(const f16x8*)&ws3h[n*NW + ko];
            bt[nt] = *(const f16x8*)&wt3h[n*NW + ko];
        }
        #pragma unroll
        for (int mt = 0; mt < 8; ++mt) {
            const f16x8 a = *(const f16x8*)&A16[(mt*16 + lr)*AST + ko];
            #pragma unroll
            for (int nt = 0; nt < 4; ++nt)
                accG[mt][nt] = __builtin_amdgcn_mfma_f32_16x16x32_f16(a, bs[nt], accG[mt][nt], 0,0,0);
        }
        const f16x8 az = *(const f16x8*)&A16[(128 + lr)*AST + ko];
        #pragma unroll
        for (int nt = 0; nt < 4; ++nt)
            accZ[nt] = __builtin_amdgcn_mfma_f32_16x16x32_f16(az, bt[nt], accZ[nt], 0,0,0);
    }

    // ---- epilogue: per-point k-max (rows 0..9 of each m-tile) ----
    // C layout: col = lane&15, row = (lane>>4)*4 + reg.
    const int rg = lg;
    #pragma unroll
    for (int mt = 0; mt < 8; ++mt) {
        #pragma unroll
        for (int nt = 0; nt < 4; ++nt) {
            float v;
            if (rg < 2)       v = fmaxf(fmaxf(accG[mt][nt][0], accG[mt][nt][1]),
                                        fmaxf(accG[mt][nt][2], accG[mt][nt][3]));
            else if (rg == 2) v = fmaxf(accG[mt][nt][0], accG[mt][nt][1]);  // rows 8,9 only
            else              v = -3.0e38f;                                  // all pad
            v = fmaxf(v, __shfl_xor(v, 16));
            v = fmaxf(v, __shfl_xor(v, 32));
            if (lane < 16) Ssm[mt][n0w + nt*16 + lane] = v;
        }
    }
    #pragma unroll
    for (int nt = 0; nt < 4; ++nt) {
        #pragma unroll
        for (int q = 0; q < 4; ++q) {
            if (rg < 2) Zr[rg*4 + q][n0w + nt*16 + lr] = accZ[nt][q];
        }
    }
    __syncthreads();

    // ---- output: 1 channel per thread, 8 points ----
    {
        const int c = t;
        const float tb = tb3[c], sb = sb3[c];
        const size_t go = ((size_t)bb*NC + c)*NPTS + n0;
        const float4 xv0 = *(const float4*)&x[go];
        const float4 xv1 = *(const float4*)&x[go + 4];
        const float xr[8] = {xv0.x,xv0.y,xv0.z,xv0.w, xv1.x,xv1.y,xv1.z,xv1.w};
        float ov[8];
        #pragma unroll
        for (int p = 0; p < 8; ++p)
            ov[p] = fmaxf(Zr[p][c] + tb + Ssm[p][c] + sb + xr[p], 0.f);
        *(float4*)&out[go]     = make_float4(ov[0],ov[1],ov[2],ov[3]);
        *(float4*)&out[go + 4] = make_float4(ov[4],ov[5],ov[6],ov[7]);
    }
}

extern "C" void kernel_launch(void* const* d_in, const int* in_sizes, int n_in,
                              void* d_out, int out_size, void* d_ws, size_t ws_size,
                              hipStream_t stream) {
    (void)in_sizes; (void)n_in; (void)out_size; (void)ws_size;
    const float* x   = (const float*)d_in[0];
    const int*   nb  = (const int*)d_in[2];
    const float* tW1 = (const float*)d_in[3];
    const float* tb1 = (const float*)d_in[4];
    const float* tW2 = (const float*)d_in[5];
    const float* tb2 = (const float*)d_in[6];
    const float* tW3 = (const float*)d_in[7];
    const float* tb3 = (const float*)d_in[8];
    const float* sW1 = (const float*)d_in[9];
    const float* sb1 = (const float*)d_in[10];
    const float* sW2 = (const float*)d_in[11];
    const float* sb2 = (const float*)d_in[12];
    const float* sW3 = (const float*)d_in[13];
    const float* sb3 = (const float*)d_in[14];
    float* out = (float*)d_out;

    float* ws  = (float*)d_ws;
    float* T1r = ws;                                   // 16000*128 f32
    float* P   = ws + (size_t)NROWS * NW;              // 16000*128 f32
    float* Q   = ws + (size_t)2 * NROWS * NW;          // 16000*128 f32
    float* xxp = ws + (size_t)3 * NROWS * NW;          // 16000 f32
    int*   tk  = (int*)(ws + (size_t)3 * NROWS * NW + NROWS);   // 16000*10 int
    _Float16* xh;
    {
        size_t off_f = (size_t)3 * NROWS * NW + NROWS + (size_t)NROWS * NK;
        xh = (_Float16*)((char*)d_ws + off_f * 4);
    }
    _Float16* xl    = xh + (size_t)NROWS * NC;         // 16000*256 f16 each
    _Float16* wt3h  = xl + (size_t)NROWS * NC;         // 256*128 f16
    _Float16* ws3h  = wt3h + NC * NW;                  // 256*128 f16

    k_prep<<<NBATCH * 32, 256, 0, stream>>>(x, xh, xl, xxp);
    k_wprep<<<32, 256, 0, stream>>>(tW3, wt3h, NC * NW);
    k_wprep<<<32, 256, 0, stream>>>(sW3, ws3h, NC * NW);
    k_rowgemm<<<dim3(NROWS / 32, 3), 256, 0, stream>>>(x, tW1, tb1, sW1, sb1, T1r, P, Q);
    k_topk<<<NBATCH * 32, 256, 0, stream>>>(xh, xl, xxp, tk);
    k_fused<<<NROWS / 8, 256, 0, stream>>>(x, nb, tk, T1r, P, Q,
                                           tW2, tb2, sW2, sb2, wt3h, ws3h, tb3, sb3, out);
}

// Round 5
// 504.914 us; speedup vs baseline: 3.5013x; 1.0213x over previous
//
#include <hip/hip_runtime.h>

#define NPTS 2000
#define NBATCH 8
#define NC 256
#define NW 128
#define NK 10
#define NROWS (NBATCH * NPTS)
#define JPAD 2048
#define PLANE (JPAD * 32)          // f16 elems per (batch, kc) plane
#define BATCHP (8 * PLANE)         // f16 elems per batch (8 kc planes)

typedef _Float16 f16x8 __attribute__((ext_vector_type(8)));
typedef _Float16 f16x4 __attribute__((ext_vector_type(4)));
typedef float f32x4 __attribute__((ext_vector_type(4)));

__device__ __forceinline__ float dot4(float4 a, float4 b) {
    return a.x*b.x + a.y*b.y + a.z*b.z + a.w*b.w;
}
__device__ __forceinline__ float4 relu4(float4 a) {
    return make_float4(fmaxf(a.x,0.f), fmaxf(a.y,0.f), fmaxf(a.z,0.f), fmaxf(a.w,0.f));
}
__device__ __forceinline__ float4 add4(float4 a, float4 b) {
    return make_float4(a.x+b.x, a.y+b.y, a.z+b.z, a.w+b.w);
}

__device__ __forceinline__ void ins10(float d, int j, float* vals, int* idxs) {
    if (d > vals[9]) {
        float v = d; int id = j;
        #pragma unroll
        for (int s = 0; s < 10; ++s) {
            if (v > vals[s]) {
                float tv = vals[s]; vals[s] = v; v = tv;
                int   ti = idxs[s]; idxs[s] = id; id = ti;
            }
        }
    }
}

// ---------------- Kernel P: transpose to K-blocked f16 hi/lo + row norms ----------------
// xbh/xbl layout: [b][kc(8)][2048 j][32 c] f16 (linear). Rows >= NPTS written as zeros.
__global__ __launch_bounds__(256) void k_prep(
    const float* __restrict__ x, _Float16* __restrict__ xbh,
    _Float16* __restrict__ xbl, float* __restrict__ xx)
{
    __shared__ float T[64][259];
    __shared__ float Pp[64][4];
    const int t  = threadIdx.x;
    const int b  = blockIdx.x >> 5;
    const int n0 = (blockIdx.x & 31) * 64;

    #pragma unroll
    for (int p = 0; p < 64; ++p) {
        const int idx = p*256 + t;
        const int c = idx >> 6, nl = idx & 63;
        T[nl][c] = x[((size_t)b*NC + c)*NPTS + min(n0 + nl, NPTS-1)];
    }
    __syncthreads();

    const int row = t & 63, q = t >> 6;   // q = 0..3 -> cc planes 2q, 2q+1
    const int gr  = n0 + row;
    const bool ok = gr < NPTS;
    float ss = 0.f;
    #pragma unroll
    for (int u = 0; u < 2; ++u) {
        const int cc = 2*q + u;
        const size_t base = (size_t)(b*8 + cc) * JPAD * 32 + (size_t)gr * 32;
        #pragma unroll
        for (int g = 0; g < 4; ++g) {
            f16x8 vh, vl;
            #pragma unroll
            for (int e = 0; e < 8; ++e) {
                const float f = ok ? T[row][cc*32 + g*8 + e] : 0.f;
                ss = fmaf(f, f, ss);
                const _Float16 h = (_Float16)f;
                vh[e] = h;
                vl[e] = (_Float16)(f - (float)h);
            }
            *(f16x8*)&xbh[base + g*8] = vh;
            *(f16x8*)&xbl[base + g*8] = vl;
        }
    }
    Pp[row][q] = ss;
    __syncthreads();
    if (t < 64 && n0 + t < NPTS)
        xx[(size_t)b*NPTS + n0 + t] = Pp[t][0] + Pp[t][1] + Pp[t][2] + Pp[t][3];
}

// ---------------- Kernel W: f32 -> f16 weight conversion ----------------
__global__ __launch_bounds__(256) void k_wprep(const float* __restrict__ a,
                                               _Float16* __restrict__ o, int n)
{
    const int i = (blockIdx.x*256 + threadIdx.x)*4;
    if (i < n) {
        const float4 v = *(const float4*)&a[i];
        f16x4 h = {(_Float16)v.x, (_Float16)v.y, (_Float16)v.z, (_Float16)v.w};
        *(f16x4*)&o[i] = h;
    }
}

// ---------------- Kernel A: row GEMM -> T1r / P / Q (unchanged) ----------------
__global__ __launch_bounds__(256) void k_rowgemm(
    const float* __restrict__ x,
    const float* __restrict__ tW1, const float* __restrict__ tb1,
    const float* __restrict__ sW1, const float* __restrict__ sb1,
    float* __restrict__ T1r, float* __restrict__ P, float* __restrict__ Q)
{
    __shared__ float Xs[32][34];
    __shared__ float Ws[32][132];
    const int t  = threadIdx.x;
    const int r0 = blockIdx.x * 32;
    const int sel = blockIdx.y;
    const int jq = t & 15,  iq = t >> 4;
    const int j0 = jq * 8,  i0 = iq * 2;

    float acc[2][8];
    #pragma unroll
    for (int a = 0; a < 2; ++a)
        #pragma unroll
        for (int q = 0; q < 8; ++q) acc[a][q] = 0.f;

    const int li = t & 31;
    const int lk = t >> 5;
    const int rl = r0 + li;
    const int lb = rl / NPTS, ln = rl % NPTS;

    for (int c0 = 0; c0 < NC; c0 += 32) {
        #pragma unroll
        for (int p = 0; p < 4; ++p) {
            int kk = lk + p * 8;
            Xs[kk][li] = x[((size_t)lb * NC + c0 + kk) * NPTS + ln];
        }
        #pragma unroll
        for (int jj = 0; jj < 16; ++jj) {
            int j = jj * 8 + lk;
            int c = c0 + li;
            float w;
            if (sel == 0)      w = tW1[j * NC + c];
            else if (sel == 1) w = sW1[j * (2*NC) + c];
            else               w = sW1[j * (2*NC) + NC + c];
            Ws[li][j] = w;
        }
        __syncthreads();
        #pragma unroll 8
        for (int kk = 0; kk < 32; ++kk) {
            const float2 xv = *(const float2*)&Xs[kk][i0];
            const float4 w0 = *(const float4*)&Ws[kk][j0];
            const float4 w1 = *(const float4*)&Ws[kk][j0 + 4];
            float w[8] = {w0.x,w0.y,w0.z,w0.w,w1.x,w1.y,w1.z,w1.w};
            #pragma unroll
            for (int q = 0; q < 8; ++q) {
                acc[0][q] = fmaf(xv.x, w[q], acc[0][q]);
                acc[1][q] = fmaf(xv.y, w[q], acc[1][q]);
            }
        }
        __syncthreads();
    }

    #pragma unroll
    for (int a = 0; a < 2; ++a) {
        const int r = r0 + i0 + a;
        float o[8];
        #pragma unroll
        for (int q = 0; q < 8; ++q) {
            float v = acc[a][q];
            if (sel == 0)      { v += tb1[j0+q]; v = fmaxf(v, 0.f); }
            else if (sel == 2) { v += sb1[j0+q]; }
            o[q] = v;
        }
        float* dst = (sel==0 ? T1r : (sel==1 ? P : Q)) + (size_t)r * NW + j0;
        *(float4*)dst       = make_float4(o[0],o[1],o[2],o[3]);
        *(float4*)(dst + 4) = make_float4(o[4],o[5],o[6],o[7]);
    }
}

// ---------------- Kernel B v3: MFMA distance GEMM, i-in-regs, reg top-10 ----------------
// Block: 16 i-rows (B-operand in regs), 4 waves each own a 32-j strip per 128-j tile.
// LDS: j-chunk double buffer (2 x 8KB hi + 2 x 8KB lo, XOR-swizzled) + xx (2x512B).
// One barrier per K-chunk. Selection fully in registers per lane (lane's i = lane&15).
__global__ __launch_bounds__(256, 2) void k_topk(
    const _Float16* __restrict__ xbh, const _Float16* __restrict__ xbl,
    const float* __restrict__ xx, int* __restrict__ tk)
{
    __shared__ __align__(16) char smem[33792];
    // [0,16384): BjH dbuf; [16384,32768): BjL dbuf; [32768,33792): xxs[2][128]
    // post-loop overlay: mval [0,10240), midx [10240,20480)

    const int t    = threadIdx.x;
    const int b    = blockIdx.x & 7;          // batch -> XCD (bid % 8)
    const int i0   = (blockIdx.x >> 3) * 16;
    const int lane = t & 63;
    const int w    = t >> 6;
    const int lr   = lane & 15;
    const int rg   = lane >> 4;
    const size_t pbase = (size_t)b * BATCHP;

    // resident i-fragments (B operand): granule rg of each 32-c chunk
    f16x8 bfh[8], bfl[8];
    #pragma unroll
    for (int kc = 0; kc < 8; ++kc) {
        const size_t a = pbase + ((size_t)kc * JPAD + i0 + lr) * 32 + rg * 8;
        bfh[kc] = *(const f16x8*)&xbh[a];
        bfl[kc] = *(const f16x8*)&xbl[a];
    }

    float vals[10]; int idxs[10];
    #pragma unroll
    for (int s = 0; s < 10; ++s) { vals[s] = -3.0e38f; idxs[s] = 0x7fffffff; }

    const int srow = t >> 1;                       // staging row 0..127
    const int sh   = t & 1;                        // granules sh and sh+2
    const int swz0 = ((sh     ^ (srow & 3)) << 4);
    const int swz1 = (((sh+2) ^ (srow & 3)) << 4);

    // prologue: stage (jt=0, kc=0) into buf 0 + xx tile 0
    {
        const size_t ga = pbase + (size_t)srow * 32 + sh * 8;
        const f16x8 h0 = *(const f16x8*)&xbh[ga];
        const f16x8 h1 = *(const f16x8*)&xbh[ga + 16];
        const f16x8 l0 = *(const f16x8*)&xbl[ga];
        const f16x8 l1 = *(const f16x8*)&xbl[ga + 16];
        *(f16x8*)(smem + srow*64 + swz0) = h0;
        *(f16x8*)(smem + srow*64 + swz1) = h1;
        *(f16x8*)(smem + 16384 + srow*64 + swz0) = l0;
        *(f16x8*)(smem + 16384 + srow*64 + swz1) = l1;
        if (t < 128)
            ((float*)(smem + 32768))[t] = xx[(size_t)b*NPTS + min(t, NPTS-1)];
    }

    const int axor  = ((rg ^ (lr & 3)) << 4);
    const int arow0 = (w*32 + lr) * 64;

    f32x4 acc0 = {0.f,0.f,0.f,0.f}, acc1 = {0.f,0.f,0.f,0.f};

    for (int jt = 0; jt < 16; ++jt) {
        #pragma unroll
        for (int kc = 0; kc < 8; ++kc) {
            __syncthreads();
            const bool hasnext = !(jt == 15 && kc == 7);
            const int njt = (kc == 7) ? jt + 1 : jt;
            const int nkc = (kc + 1) & 7;
            f16x8 h0, h1, l0, l1; float xv = 0.f;
            if (hasnext) {   // issue coalesced loads for next chunk (hide under MFMA)
                const size_t ga = pbase + ((size_t)nkc*JPAD + njt*128 + srow)*32 + sh*8;
                h0 = *(const f16x8*)&xbh[ga];
                h1 = *(const f16x8*)&xbh[ga + 16];
                l0 = *(const f16x8*)&xbl[ga];
                l1 = *(const f16x8*)&xbl[ga + 16];
                if (kc == 7 && t < 128)
                    xv = xx[(size_t)b*NPTS + min(njt*128 + t, NPTS-1)];
            }

            {   // A-fragments (j) from LDS buf kc&1, 3-pass hi/lo MFMA
                const char* BH = smem + (kc & 1)*8192;
                const char* BL = smem + 16384 + (kc & 1)*8192;
                const f16x8 a0h = *(const f16x8*)(BH + arow0 + axor);
                const f16x8 a1h = *(const f16x8*)(BH + arow0 + 1024 + axor);
                const f16x8 a0l = *(const f16x8*)(BL + arow0 + axor);
                const f16x8 a1l = *(const f16x8*)(BL + arow0 + 1024 + axor);
                acc0 = __builtin_amdgcn_mfma_f32_16x16x32_f16(a0h, bfh[kc], acc0, 0,0,0);
                acc1 = __builtin_amdgcn_mfma_f32_16x16x32_f16(a1h, bfh[kc], acc1, 0,0,0);
                acc0 = __builtin_amdgcn_mfma_f32_16x16x32_f16(a0h, bfl[kc], acc0, 0,0,0);
                acc1 = __builtin_amdgcn_mfma_f32_16x16x32_f16(a1h, bfl[kc], acc1, 0,0,0);
                acc0 = __builtin_amdgcn_mfma_f32_16x16x32_f16(a0l, bfh[kc], acc0, 0,0,0);
                acc1 = __builtin_amdgcn_mfma_f32_16x16x32_f16(a1l, bfh[kc], acc1, 0,0,0);
            }

            if (hasnext) {   // write next chunk into the other buffer
                char* WH = smem + ((kc+1) & 1)*8192;
                char* WL = smem + 16384 + ((kc+1) & 1)*8192;
                *(f16x8*)(WH + srow*64 + swz0) = h0;
                *(f16x8*)(WH + srow*64 + swz1) = h1;
                *(f16x8*)(WL + srow*64 + swz0) = l0;
                *(f16x8*)(WL + srow*64 + swz1) = l1;
                if (kc == 7 && t < 128)
                    ((float*)(smem + 32768 + ((jt+1)&1)*512))[t] = xv;
            }
        }

        // selection for this jt: lane owns i = i0+lr, j's ascending (m, then q)
        {
            const float* xxv = (const float*)(smem + 32768 + (jt & 1)*512);
            const int lo = w*32 + rg*4;
            const int jb = jt*128 + lo;
            #pragma unroll
            for (int q = 0; q < 4; ++q) {
                const int j = jb + q;
                if (j < NPTS) ins10(2.f*acc0[q] - xxv[lo + q], j, vals, idxs);
            }
            #pragma unroll
            for (int q = 0; q < 4; ++q) {
                const int j = jb + 16 + q;
                if (j < NPTS) ins10(2.f*acc1[q] - xxv[lo + 16 + q], j, vals, idxs);
            }
            acc0 = (f32x4){0.f,0.f,0.f,0.f};
            acc1 = (f32x4){0.f,0.f,0.f,0.f};
        }
    }

    __syncthreads();
    float* mval = (float*)smem;
    int*   midx = (int*)(smem + 10240);
    {
        const int base = (lr*16 + w*4 + rg)*10;
        #pragma unroll
        for (int s = 0; s < 10; ++s) { mval[base+s] = vals[s]; midx[base+s] = idxs[s]; }
    }
    __syncthreads();

#define MSTEP(S)                                                              \
    if (t < 16*(S)) {                                                         \
        const int i_ = t / (S), l_ = t % (S);                                 \
        float* va = &mval[(i_*16 + l_)*10];                                   \
        int*   ia = &midx[(i_*16 + l_)*10];                                   \
        const float* vb = &mval[(i_*16 + l_ + (S))*10];                       \
        const int*   ib = &midx[(i_*16 + l_ + (S))*10];                       \
        float ov[10]; int oi[10]; int pa = 0, pb = 0;                         \
        _Pragma("unroll")                                                     \
        for (int s = 0; s < 10; ++s) {                                        \
            const float A = va[pa], Bv = vb[pb];                              \
            const int  Ai = ia[pa], Bi = ib[pb];                              \
            const bool ta = (A > Bv) || (A == Bv && Ai < Bi);                 \
            ov[s] = ta ? A : Bv; oi[s] = ta ? Ai : Bi;                        \
            pa += ta ? 1 : 0; pb += ta ? 0 : 1;                               \
        }                                                                     \
        _Pragma("unroll")                                                     \
        for (int s = 0; s < 10; ++s) { va[s] = ov[s]; ia[s] = oi[s]; }        \
    }                                                                         \
    __syncthreads();

    MSTEP(8) MSTEP(4) MSTEP(2)
#undef MSTEP

    if (t < 16) {
        const float* va = &mval[(t*16 + 0)*10]; const int* ia = &midx[(t*16 + 0)*10];
        const float* vb = &mval[(t*16 + 1)*10]; const int* ib = &midx[(t*16 + 1)*10];
        int* op = &tk[(size_t)(b*NPTS + i0 + t)*NK];
        int pa = 0, pb = 0;
        #pragma unroll
        for (int s = 0; s < 10; ++s) {
            const float A = va[pa], Bv = vb[pb];
            const int  Ai = ia[pa], Bi = ib[pb];
            const bool ta = (A > Bv) || (A == Bv && Ai < Bi);
            op[s] = b*NPTS + (ta ? Ai : Bi);
            pa += ta ? 1 : 0; pb += ta ? 0 : 1;
        }
    }
}

// ---------------- Kernel D: fused tail (MFMA phase 2, unchanged from R4) ----------------
#define AST 136
__global__ __launch_bounds__(256, 2) void k_fused(
    const float* __restrict__ x,
    const int* __restrict__ nb, const int* __restrict__ tk,
    const float* __restrict__ T1r, const float* __restrict__ P, const float* __restrict__ Q,
    const float* __restrict__ tW2, const float* __restrict__ tb2,
    const float* __restrict__ sW2, const float* __restrict__ sb2,
    const _Float16* __restrict__ wt3h, const _Float16* __restrict__ ws3h,
    const float* __restrict__ tb3, const float* __restrict__ sb3,
    float* __restrict__ out)
{
    __shared__ __align__(16) _Float16 A16[144*AST];
    __shared__ float Ssm[8][260];
    __shared__ float Zr[8][260];

    const int t  = threadIdx.x;
    const int r0 = blockIdx.x * 8;
    const int bb = r0 / NPTS;
    const int n0 = r0 % NPTS;

    {
        const float4 z4 = make_float4(0.f,0.f,0.f,0.f);
        float4* p4 = (float4*)A16;
        #pragma unroll
        for (int i = 0; i < 10; ++i) {
            const int idx = t + i*256;
            if (idx < 2448) p4[idx] = z4;
        }
    }
    __syncthreads();

    {
        const int o    = t & 127;
        const int half = t >> 7;
        const int g4   = o & ~3;

        const float4 f0 = *(const float4*)&tW2[o*12];
        const float4 f1 = *(const float4*)&tW2[o*12 + 4];
        const float4 f2 = *(const float4*)&tW2[o*12 + 8];
        const float4 wt0 = make_float4(f0.x, f0.w, f1.z, f2.y);
        const float4 wt1 = make_float4(f0.y, f1.x, f1.w, f2.z);
        const float4 wt2 = make_float4(f0.z, f1.y, f2.x, f2.w);
        const float4 wsw = *(const float4*)&sW2[o*4];
        const float tb2o = tb2[o], sb2o = sb2[o];

        #pragma unroll
        for (int ptl = 0; ptl < 4; ++ptl) {
            const int pt = half*4 + ptl;
            const int r  = r0 + pt;
            const int nb0 = nb[r*3+0], nb1 = nb[r*3+1], nb2 = nb[r*3+2];
            int ki[NK];
            #pragma unroll
            for (int k = 0; k < NK; ++k) ki[k] = tk[r*NK + k];
            const float4 h0 = *(const float4*)&T1r[(size_t)nb0*NW + g4];
            const float4 h1 = *(const float4*)&T1r[(size_t)nb1*NW + g4];
            const float4 h2 = *(const float4*)&T1r[(size_t)nb2*NW + g4];
            const float4 qf = *(const float4*)&Q[(size_t)r*NW + g4];
            float4 pf[NK];
            #pragma unroll
            for (int k = 0; k < NK; ++k) pf[k] = *(const float4*)&P[(size_t)ki[k]*NW + g4];

            const float z = tb2o + dot4(wt0,h0) + dot4(wt1,h1) + dot4(wt2,h2);
            A16[(128 + pt)*AST + o] = (_Float16)fmaxf(z, 0.f);
            #pragma unroll
            for (int k = 0; k < NK; ++k) {
                const float4 g1 = relu4(add4(pf[k], qf));
                A16[(pt*16 + k)*AST + o] = (_Float16)fmaxf(dot4(wsw, g1) + sb2o, 0.f);
            }
        }
    }
    __syncthreads();

    const int lane = t & 63, w = t >> 6;
    const int lr = lane & 15, lg = lane >> 4;
    const int n0w = w * 64;

    f32x4 accG[8][4] = {};
    f32x4 accZ[4] = {};

    #pragma unroll
    for (int kt = 0; kt < 4; ++kt) {
        const int ko = kt*32 + lg*8;
        f16x8 bs[4], bt[4];
        #pragma unroll
        for (int nt = 0; nt < 4; ++nt) {
            const int n = n0w + nt*16 + lr;
            bs[nt] = *(const f16x8*)&ws3h[n*NW + ko];
            bt[nt] = *(const f16x8*)&wt3h[n*NW + ko];
        }
        #pragma unroll
        for (int mt = 0; mt < 8; ++mt) {
            const f16x8 a = *(const f16x8*)&A16[(mt*16 + lr)*AST + ko];
            #pragma unroll
            for (int nt = 0; nt < 4; ++nt)
                accG[mt][nt] = __builtin_amdgcn_mfma_f32_16x16x32_f16(a, bs[nt], accG[mt][nt], 0,0,0);
        }
        const f16x8 az = *(const f16x8*)&A16[(128 + lr)*AST + ko];
        #pragma unroll
        for (int nt = 0; nt < 4; ++nt)
            accZ[nt] = __builtin_amdgcn_mfma_f32_16x16x32_f16(az, bt[nt], accZ[nt], 0,0,0);
    }

    const int rg = lg;
    #pragma unroll
    for (int mt = 0; mt < 8; ++mt) {
        #pragma unroll
        for (int nt = 0; nt < 4; ++nt) {
            float v;
            if (rg < 2)       v = fmaxf(fmaxf(accG[mt][nt][0], accG[mt][nt][1]),
                                        fmaxf(accG[mt][nt][2], accG[mt][nt][3]));
            else if (rg == 2) v = fmaxf(accG[mt][nt][0], accG[mt][nt][1]);
            else              v = -3.0e38f;
            v = fmaxf(v, __shfl_xor(v, 16));
            v = fmaxf(v, __shfl_xor(v, 32));
            if (lane < 16) Ssm[mt][n0w + nt*16 + lane] = v;
        }
    }
    #pragma unroll
    for (int nt = 0; nt < 4; ++nt) {
        #pragma unroll
        for (int q = 0; q < 4; ++q) {
            if (rg < 2) Zr[rg*4 + q][n0w + nt*16 + lr] = accZ[nt][q];
        }
    }
    __syncthreads();

    {
        const int c = t;
        const float tb = tb3[c], sb = sb3[c];
        const size_t go = ((size_t)bb*NC + c)*NPTS + n0;
        const float4 xv0 = *(const float4*)&x[go];
        const float4 xv1 = *(const float4*)&x[go + 4];
        const float xr[8] = {xv0.x,xv0.y,xv0.z,xv0.w, xv1.x,xv1.y,xv1.z,xv1.w};
        float ov[8];
        #pragma unroll
        for (int p = 0; p < 8; ++p)
            ov[p] = fmaxf(Zr[p][c] + tb + Ssm[p][c] + sb + xr[p], 0.f);
        *(float4*)&out[go]     = make_float4(ov[0],ov[1],ov[2],ov[3]);
        *(float4*)&out[go + 4] = make_float4(ov[4],ov[5],ov[6],ov[7]);
    }
}

extern "C" void kernel_launch(void* const* d_in, const int* in_sizes, int n_in,
                              void* d_out, int out_size, void* d_ws, size_t ws_size,
                              hipStream_t stream) {
    (void)in_sizes; (void)n_in; (void)out_size; (void)ws_size;
    const float* x   = (const float*)d_in[0];
    const int*   nb  = (const int*)d_in[2];
    const float* tW1 = (const float*)d_in[3];
    const float* tb1 = (const float*)d_in[4];
    const float* tW2 = (const float*)d_in[5];
    const float* tb2 = (const float*)d_in[6];
    const float* tW3 = (const float*)d_in[7];
    const float* tb3 = (const float*)d_in[8];
    const float* sW1 = (const float*)d_in[9];
    const float* sb1 = (const float*)d_in[10];
    const float* sW2 = (const float*)d_in[11];
    const float* sb2 = (const float*)d_in[12];
    const float* sW3 = (const float*)d_in[13];
    const float* sb3 = (const float*)d_in[14];
    float* out = (float*)d_out;

    float* ws  = (float*)d_ws;
    float* T1r = ws;                                   // 16000*128 f32
    float* P   = ws + (size_t)NROWS * NW;              // 16000*128 f32
    float* Q   = ws + (size_t)2 * NROWS * NW;          // 16000*128 f32
    float* xxp = ws + (size_t)3 * NROWS * NW;          // 16000 f32
    int*   tk  = (int*)(ws + (size_t)3 * NROWS * NW + NROWS);   // 16000*10 int
    _Float16* xbh;
    {
        size_t off_f = (size_t)3 * NROWS * NW + NROWS + (size_t)NROWS * NK;
        xbh = (_Float16*)((char*)d_ws + off_f * 4);
    }
    _Float16* xbl  = xbh + (size_t)NBATCH * BATCHP;    // 4,194,304 f16 each
    _Float16* wt3h = xbl + (size_t)NBATCH * BATCHP;    // 256*128 f16
    _Float16* ws3h = wt3h + NC * NW;                   // 256*128 f16

    k_prep<<<NBATCH * 32, 256, 0, stream>>>(x, xbh, xbl, xxp);
    k_wprep<<<32, 256, 0, stream>>>(tW3, wt3h, NC * NW);
    k_wprep<<<32, 256, 0, stream>>>(sW3, ws3h, NC * NW);
    k_rowgemm<<<dim3(NROWS / 32, 3), 256, 0, stream>>>(x, tW1, tb1, sW1, sb1, T1r, P, Q);
    k_topk<<<NBATCH * (NPTS / 16), 256, 0, stream>>>(xbh, xbl, xxp, tk);
    k_fused<<<NROWS / 8, 256, 0, stream>>>(x, nb, tk, T1r, P, Q,
                                           tW2, tb2, sW2, sb2, wt3h, ws3h, tb3, sb3, out);
}

// Round 6
// 467.229 us; speedup vs baseline: 3.7837x; 1.0807x over previous
//
#include <hip/hip_runtime.h>

#define NPTS 2000
#define NBATCH 8
#define NC 256
#define NW 128
#define NK 10
#define NROWS (NBATCH * NPTS)
#define JPAD 2048
#define PLANE (JPAD * 64)          // f16 elems per (batch, kc) plane: 2048 rows x 64 (hi+lo interleaved slots)

typedef _Float16 f16x8 __attribute__((ext_vector_type(8)));
typedef _Float16 f16x4 __attribute__((ext_vector_type(4)));
typedef float f32x4 __attribute__((ext_vector_type(4)));

__device__ __forceinline__ float dot4(float4 a, float4 b) {
    return a.x*b.x + a.y*b.y + a.z*b.z + a.w*b.w;
}
__device__ __forceinline__ float4 relu4(float4 a) {
    return make_float4(fmaxf(a.x,0.f), fmaxf(a.y,0.f), fmaxf(a.z,0.f), fmaxf(a.w,0.f));
}
__device__ __forceinline__ float4 add4(float4 a, float4 b) {
    return make_float4(a.x+b.x, a.y+b.y, a.z+b.z, a.w+b.w);
}

__device__ __forceinline__ void ins10(float d, int j, float* vals, int* idxs) {
    if (d > vals[9]) {
        float v = d; int id = j;
        #pragma unroll
        for (int s = 0; s < 10; ++s) {
            if (v > vals[s]) {
                float tv = vals[s]; vals[s] = v; v = tv;
                int   ti = idxs[s]; idxs[s] = id; id = ti;
            }
        }
    }
}

__device__ __forceinline__ void gl_lds16(const void* g, void* l) {
    __builtin_amdgcn_global_load_lds(
        (const __attribute__((address_space(1))) void*)g,
        (__attribute__((address_space(3))) void*)l, 16, 0, 0);
}

// ---------------- Kernel P: transpose to swizzled K-blocked f16 hi/lo + row norms ----------------
// xb layout: [b][kc(8)][2048 j][8 slots x 8 f16]; slot(hl,g,row) = ((hl<<2)|g) ^ (row&7).
// Rows >= NPTS zero-filled.
__global__ __launch_bounds__(256) void k_prep(
    const float* __restrict__ x, _Float16* __restrict__ xb,
    float* __restrict__ xx)
{
    __shared__ float T[64][259];
    __shared__ float Pp[64][4];
    const int t  = threadIdx.x;
    const int b  = blockIdx.x >> 5;
    const int n0 = (blockIdx.x & 31) * 64;

    #pragma unroll
    for (int p = 0; p < 64; ++p) {
        const int idx = p*256 + t;
        const int c = idx >> 6, nl = idx & 63;
        T[nl][c] = x[((size_t)b*NC + c)*NPTS + min(n0 + nl, NPTS-1)];
    }
    __syncthreads();

    const int row = t & 63, q = t >> 6;   // q = 0..3 -> kc planes 2q, 2q+1
    const int gr  = n0 + row;
    const bool ok = gr < NPTS;
    const int rx  = gr & 7;
    float ss = 0.f;
    #pragma unroll
    for (int u = 0; u < 2; ++u) {
        const int kc = 2*q + u;
        const size_t base = ((size_t)(b*8 + kc) * JPAD + gr) * 64;
        #pragma unroll
        for (int g = 0; g < 4; ++g) {
            f16x8 vh, vl;
            #pragma unroll
            for (int e = 0; e < 8; ++e) {
                const float f = ok ? T[row][kc*32 + g*8 + e] : 0.f;
                ss = fmaf(f, f, ss);
                const _Float16 h = (_Float16)f;
                vh[e] = h;
                vl[e] = (_Float16)(f - (float)h);
            }
            *(f16x8*)&xb[base + (size_t)((g      ^ rx)) * 8] = vh;
            *(f16x8*)&xb[base + (size_t)(((4|g)  ^ rx)) * 8] = vl;
        }
    }
    Pp[row][q] = ss;
    __syncthreads();
    if (t < 64 && n0 + t < NPTS)
        xx[(size_t)b*NPTS + n0 + t] = Pp[t][0] + Pp[t][1] + Pp[t][2] + Pp[t][3];
}

// ---------------- Kernel W: f32 -> f16 weight conversion ----------------
__global__ __launch_bounds__(256) void k_wprep(const float* __restrict__ a,
                                               _Float16* __restrict__ o, int n)
{
    const int i = (blockIdx.x*256 + threadIdx.x)*4;
    if (i < n) {
        const float4 v = *(const float4*)&a[i];
        f16x4 h = {(_Float16)v.x, (_Float16)v.y, (_Float16)v.z, (_Float16)v.w};
        *(f16x4*)&o[i] = h;
    }
}

// ---------------- Kernel A: row GEMM -> T1r / P / Q (unchanged) ----------------
__global__ __launch_bounds__(256) void k_rowgemm(
    const float* __restrict__ x,
    const float* __restrict__ tW1, const float* __restrict__ tb1,
    const float* __restrict__ sW1, const float* __restrict__ sb1,
    float* __restrict__ T1r, float* __restrict__ P, float* __restrict__ Q)
{
    __shared__ float Xs[32][34];
    __shared__ float Ws[32][132];
    const int t  = threadIdx.x;
    const int r0 = blockIdx.x * 32;
    const int sel = blockIdx.y;
    const int jq = t & 15,  iq = t >> 4;
    const int j0 = jq * 8,  i0 = iq * 2;

    float acc[2][8];
    #pragma unroll
    for (int a = 0; a < 2; ++a)
        #pragma unroll
        for (int q = 0; q < 8; ++q) acc[a][q] = 0.f;

    const int li = t & 31;
    const int lk = t >> 5;
    const int rl = r0 + li;
    const int lb = rl / NPTS, ln = rl % NPTS;

    for (int c0 = 0; c0 < NC; c0 += 32) {
        #pragma unroll
        for (int p = 0; p < 4; ++p) {
            int kk = lk + p * 8;
            Xs[kk][li] = x[((size_t)lb * NC + c0 + kk) * NPTS + ln];
        }
        #pragma unroll
        for (int jj = 0; jj < 16; ++jj) {
            int j = jj * 8 + lk;
            int c = c0 + li;
            float w;
            if (sel == 0)      w = tW1[j * NC + c];
            else if (sel == 1) w = sW1[j * (2*NC) + c];
            else               w = sW1[j * (2*NC) + NC + c];
            Ws[li][j] = w;
        }
        __syncthreads();
        #pragma unroll 8
        for (int kk = 0; kk < 32; ++kk) {
            const float2 xv = *(const float2*)&Xs[kk][i0];
            const float4 w0 = *(const float4*)&Ws[kk][j0];
            const float4 w1 = *(const float4*)&Ws[kk][j0 + 4];
            float w[8] = {w0.x,w0.y,w0.z,w0.w,w1.x,w1.y,w1.z,w1.w};
            #pragma unroll
            for (int q = 0; q < 8; ++q) {
                acc[0][q] = fmaf(xv.x, w[q], acc[0][q]);
                acc[1][q] = fmaf(xv.y, w[q], acc[1][q]);
            }
        }
        __syncthreads();
    }

    #pragma unroll
    for (int a = 0; a < 2; ++a) {
        const int r = r0 + i0 + a;
        float o[8];
        #pragma unroll
        for (int q = 0; q < 8; ++q) {
            float v = acc[a][q];
            if (sel == 0)      { v += tb1[j0+q]; v = fmaxf(v, 0.f); }
            else if (sel == 2) { v += sb1[j0+q]; }
            o[q] = v;
        }
        float* dst = (sel==0 ? T1r : (sel==1 ? P : Q)) + (size_t)r * NW + j0;
        *(float4*)dst       = make_float4(o[0],o[1],o[2],o[3]);
        *(float4*)(dst + 4) = make_float4(o[4],o[5],o[6],o[7]);
    }
}

// ---------------- Kernel B v4: MFMA distance GEMM, DMA staging, reg top-10 ----------------
// Block: 16 i-rows (B-operand resident in regs from swizzled global), 4 waves x 32-j strips.
// Staging: global_load_lds width-16, LDS linear (swizzle pre-baked in global layout).
// 2x16KB double buffer; one barrier per (jt,kc); 3 blocks/CU.
__global__ __launch_bounds__(256, 3) void k_topk(
    const _Float16* __restrict__ xb, const float* __restrict__ xx,
    int* __restrict__ tk)
{
    __shared__ __align__(16) char smem[32768];

    const int t    = threadIdx.x;
    const int b    = blockIdx.x & 7;          // batch -> XCD
    const int i0   = (blockIdx.x >> 3) * 16;
    const int lane = t & 63;
    const int w    = t >> 6;
    const int lr   = lane & 15;
    const int rg   = lane >> 4;
    const size_t pbase_e = (size_t)b * 8 * PLANE;

    // resident i-fragments (B operand) from swizzled layout
    f16x8 bfh[8], bfl[8];
    {
        const int ix = lr & 7;
        #pragma unroll
        for (int kc = 0; kc < 8; ++kc) {
            const size_t ro = pbase_e + (size_t)kc*PLANE + (size_t)(i0 + lr)*64;
            bfh[kc] = *(const f16x8*)&xb[ro + (size_t)((rg     ^ ix))*8];
            bfl[kc] = *(const f16x8*)&xb[ro + (size_t)(((4|rg) ^ ix))*8];
        }
    }

    float vals[10]; int idxs[10];
    #pragma unroll
    for (int s = 0; s < 10; ++s) { vals[s] = -3.0e38f; idxs[s] = 0x7fffffff; }

    // staging pointers: chunk (w*4+q) = 8 rows x 128 B; per-lane 16 B
    const char* gs0 = (const char*)xb + pbase_e*2 + (size_t)(w*4)*1024 + (size_t)lane*16;
    char* ld0 = smem + (w*4)*1024;

    // prologue: stage (jt=0, kc=0) into buf 0
    #pragma unroll
    for (int q = 0; q < 4; ++q) gl_lds16(gs0 + q*1024, ld0 + q*1024);

    const int axh = ((rg     ^ (lr & 7))) * 16;
    const int axl = (((4|rg) ^ (lr & 7))) * 16;
    const int arow = (w*32 + lr) * 128;

    f32x4 acc0 = {0.f,0.f,0.f,0.f}, acc1 = {0.f,0.f,0.f,0.f};
    const float* xxp = xx + (size_t)b * NPTS;

    for (int jt = 0; jt < 16; ++jt) {
        #pragma unroll
        for (int kc = 0; kc < 8; ++kc) {
            __syncthreads();
            const int buf = kc & 1;

            // prefetch next chunk into buf^1 (DMA; drained by NEXT barrier)
            if (!(jt == 15 && kc == 7)) {
                const int nkc = (kc + 1) & 7;
                const int njt = (kc == 7) ? jt + 1 : jt;
                const size_t noff = (size_t)nkc * (PLANE*2) + (size_t)njt * 16384;
                const char* gs = gs0 + noff;
                char* ld = ld0 + (buf ^ 1)*16384;
                #pragma unroll
                for (int q = 0; q < 4; ++q) gl_lds16(gs + q*1024, ld + q*1024);
            }

            // compute on buf
            {
                const char* Bb = smem + buf*16384;
                const f16x8 a0h = *(const f16x8*)(Bb + arow + axh);
                const f16x8 a0l = *(const f16x8*)(Bb + arow + axl);
                const f16x8 a1h = *(const f16x8*)(Bb + arow + 2048 + axh);
                const f16x8 a1l = *(const f16x8*)(Bb + arow + 2048 + axl);
                acc0 = __builtin_amdgcn_mfma_f32_16x16x32_f16(a0h, bfh[kc], acc0, 0,0,0);
                acc1 = __builtin_amdgcn_mfma_f32_16x16x32_f16(a1h, bfh[kc], acc1, 0,0,0);
                acc0 = __builtin_amdgcn_mfma_f32_16x16x32_f16(a0h, bfl[kc], acc0, 0,0,0);
                acc1 = __builtin_amdgcn_mfma_f32_16x16x32_f16(a1h, bfl[kc], acc1, 0,0,0);
                acc0 = __builtin_amdgcn_mfma_f32_16x16x32_f16(a0l, bfh[kc], acc0, 0,0,0);
                acc1 = __builtin_amdgcn_mfma_f32_16x16x32_f16(a1l, bfh[kc], acc1, 0,0,0);
            }
        }

        // selection for this jt (lane's i = i0+lr; j ascending -> tie rule kept)
        {
            const int jb = jt*128 + w*32 + rg*4;
            const f32x4 xv0 = *(const f32x4*)&xxp[min(jb,      NPTS-4)];
            const f32x4 xv1 = *(const f32x4*)&xxp[min(jb + 16, NPTS-4)];
            #pragma unroll
            for (int q = 0; q < 4; ++q) {
                const int j = jb + q;
                if (j < NPTS) ins10(2.f*acc0[q] - xv0[q], j, vals, idxs);
            }
            #pragma unroll
            for (int q = 0; q < 4; ++q) {
                const int j = jb + 16 + q;
                if (j < NPTS) ins10(2.f*acc1[q] - xv1[q], j, vals, idxs);
            }
            acc0 = (f32x4){0.f,0.f,0.f,0.f};
            acc1 = (f32x4){0.f,0.f,0.f,0.f};
        }
    }

    __syncthreads();
    float* mval = (float*)smem;
    int*   midx = (int*)(smem + 10240);
    {
        const int base = (lr*16 + w*4 + rg)*10;
        #pragma unroll
        for (int s = 0; s < 10; ++s) { mval[base+s] = vals[s]; midx[base+s] = idxs[s]; }
    }
    __syncthreads();

#define MSTEP(S)                                                              \
    if (t < 16*(S)) {                                                         \
        const int i_ = t / (S), l_ = t % (S);                                 \
        float* va = &mval[(i_*16 + l_)*10];                                   \
        int*   ia = &midx[(i_*16 + l_)*10];                                   \
        const float* vb = &mval[(i_*16 + l_ + (S))*10];                       \
        const int*   ib = &midx[(i_*16 + l_ + (S))*10];                       \
        float ov[10]; int oi[10]; int pa = 0, pb = 0;                         \
        _Pragma("unroll")                                                     \
        for (int s = 0; s < 10; ++s) {                                        \
            const float A = va[pa], Bv = vb[pb];                              \
            const int  Ai = ia[pa], Bi = ib[pb];                              \
            const bool ta = (A > Bv) || (A == Bv && Ai < Bi);                 \
            ov[s] = ta ? A : Bv; oi[s] = ta ? Ai : Bi;                        \
            pa += ta ? 1 : 0; pb += ta ? 0 : 1;                               \
        }                                                                     \
        _Pragma("unroll")                                                     \
        for (int s = 0; s < 10; ++s) { va[s] = ov[s]; ia[s] = oi[s]; }        \
    }                                                                         \
    __syncthreads();

    MSTEP(8) MSTEP(4) MSTEP(2)
#undef MSTEP

    if (t < 16) {
        const float* va = &mval[(t*16 + 0)*10]; const int* ia = &midx[(t*16 + 0)*10];
        const float* vb = &mval[(t*16 + 1)*10]; const int* ib = &midx[(t*16 + 1)*10];
        int* op = &tk[(size_t)(b*NPTS + i0 + t)*NK];
        int pa = 0, pb = 0;
        #pragma unroll
        for (int s = 0; s < 10; ++s) {
            const float A = va[pa], Bv = vb[pb];
            const int  Ai = ia[pa], Bi = ib[pb];
            const bool ta = (A > Bv) || (A == Bv && Ai < Bi);
            op[s] = b*NPTS + (ta ? Ai : Bi);
            pa += ta ? 1 : 0; pb += ta ? 0 : 1;
        }
    }
}

// ---------------- Kernel D: fused tail (MFMA phase 2, unchanged) ----------------
#define AST 136
__global__ __launch_bounds__(256, 2) void k_fused(
    const float* __restrict__ x,
    const int* __restrict__ nb, const int* __restrict__ tk,
    const float* __restrict__ T1r, const float* __restrict__ P, const float* __restrict__ Q,
    const float* __restrict__ tW2, const float* __restrict__ tb2,
    const float* __restrict__ sW2, const float* __restrict__ sb2,
    const _Float16* __restrict__ wt3h, const _Float16* __restrict__ ws3h,
    const float* __restrict__ tb3, const float* __restrict__ sb3,
    float* __restrict__ out)
{
    __shared__ __align__(16) _Float16 A16[144*AST];
    __shared__ float Ssm[8][260];
    __shared__ float Zr[8][260];

    const int t  = threadIdx.x;
    const int r0 = blockIdx.x * 8;
    const int bb = r0 / NPTS;
    const int n0 = r0 % NPTS;

    {
        const float4 z4 = make_float4(0.f,0.f,0.f,0.f);
        float4* p4 = (float4*)A16;
        #pragma unroll
        for (int i = 0; i < 10; ++i) {
            const int idx = t + i*256;
            if (idx < 2448) p4[idx] = z4;
        }
    }
    __syncthreads();

    {
        const int o    = t & 127;
        const int half = t >> 7;
        const int g4   = o & ~3;

        const float4 f0 = *(const float4*)&tW2[o*12];
        const float4 f1 = *(const float4*)&tW2[o*12 + 4];
        const float4 f2 = *(const float4*)&tW2[o*12 + 8];
        const float4 wt0 = make_float4(f0.x, f0.w, f1.z, f2.y);
        const float4 wt1 = make_float4(f0.y, f1.x, f1.w, f2.z);
        const float4 wt2 = make_float4(f0.z, f1.y, f2.x, f2.w);
        const float4 wsw = *(const float4*)&sW2[o*4];
        const float tb2o = tb2[o], sb2o = sb2[o];

        #pragma unroll
        for (int ptl = 0; ptl < 4; ++ptl) {
            const int pt = half*4 + ptl;
            const int r  = r0 + pt;
            const int nb0 = nb[r*3+0], nb1 = nb[r*3+1], nb2 = nb[r*3+2];
            int ki[NK];
            #pragma unroll
            for (int k = 0; k < NK; ++k) ki[k] = tk[r*NK + k];
            const float4 h0 = *(const float4*)&T1r[(size_t)nb0*NW + g4];
            const float4 h1 = *(const float4*)&T1r[(size_t)nb1*NW + g4];
            const float4 h2 = *(const float4*)&T1r[(size_t)nb2*NW + g4];
            const float4 qf = *(const float4*)&Q[(size_t)r*NW + g4];
            float4 pf[NK];
            #pragma unroll
            for (int k = 0; k < NK; ++k) pf[k] = *(const float4*)&P[(size_t)ki[k]*NW + g4];

            const float z = tb2o + dot4(wt0,h0) + dot4(wt1,h1) + dot4(wt2,h2);
            A16[(128 + pt)*AST + o] = (_Float16)fmaxf(z, 0.f);
            #pragma unroll
            for (int k = 0; k < NK; ++k) {
                const float4 g1 = relu4(add4(pf[k], qf));
                A16[(pt*16 + k)*AST + o] = (_Float16)fmaxf(dot4(wsw, g1) + sb2o, 0.f);
            }
        }
    }
    __syncthreads();

    const int lane = t & 63, w = t >> 6;
    const int lr = lane & 15, lg = lane >> 4;
    const int n0w = w * 64;

    f32x4 accG[8][4] = {};
    f32x4 accZ[4] = {};

    #pragma unroll
    for (int kt = 0; kt < 4; ++kt) {
        const int ko = kt*32 + lg*8;
        f16x8 bs[4], bt[4];
        #pragma unroll
        for (int nt = 0; nt < 4; ++nt) {
            const int n = n0w + nt*16 + lr;
            bs[nt] = *(const f16x8*)&ws3h[n*NW + ko];
            bt[nt] = *(const f16x8*)&wt3h[n*NW + ko];
        }
        #pragma unroll
        for (int mt = 0; mt < 8; ++mt) {
            const f16x8 a = *(const f16x8*)&A16[(mt*16 + lr)*AST + ko];
            #pragma unroll
            for (int nt = 0; nt < 4; ++nt)
                accG[mt][nt] = __builtin_amdgcn_mfma_f32_16x16x32_f16(a, bs[nt], accG[mt][nt], 0,0,0);
        }
        const f16x8 az = *(const f16x8*)&A16[(128 + lr)*AST + ko];
        #pragma unroll
        for (int nt = 0; nt < 4; ++nt)
            accZ[nt] = __builtin_amdgcn_mfma_f32_16x16x32_f16(az, bt[nt], accZ[nt], 0,0,0);
    }

    const int rg = lg;
    #pragma unroll
    for (int mt = 0; mt < 8; ++mt) {
        #pragma unroll
        for (int nt = 0; nt < 4; ++nt) {
            float v;
            if (rg < 2)       v = fmaxf(fmaxf(accG[mt][nt][0], accG[mt][nt][1]),
                                        fmaxf(accG[mt][nt][2], accG[mt][nt][3]));
            else if (rg == 2) v = fmaxf(accG[mt][nt][0], accG[mt][nt][1]);
            else              v = -3.0e38f;
            v = fmaxf(v, __shfl_xor(v, 16));
            v = fmaxf(v, __shfl_xor(v, 32));
            if (lane < 16) Ssm[mt][n0w + nt*16 + lane] = v;
        }
    }
    #pragma unroll
    for (int nt = 0; nt < 4; ++nt) {
        #pragma unroll
        for (int q = 0; q < 4; ++q) {
            if (rg < 2) Zr[rg*4 + q][n0w + nt*16 + lr] = accZ[nt][q];
        }
    }
    __syncthreads();

    {
        const int c = t;
        const float tb = tb3[c], sb = sb3[c];
        const size_t go = ((size_t)bb*NC + c)*NPTS + n0;
        const float4 xv0 = *(const float4*)&x[go];
        const float4 xv1 = *(const float4*)&x[go + 4];
        const float xr[8] = {xv0.x,xv0.y,xv0.z,xv0.w, xv1.x,xv1.y,xv1.z,xv1.w};
        float ov[8];
        #pragma unroll
        for (int p = 0; p < 8; ++p)
            ov[p] = fmaxf(Zr[p][c] + tb + Ssm[p][c] + sb + xr[p], 0.f);
        *(float4*)&out[go]     = make_float4(ov[0],ov[1],ov[2],ov[3]);
        *(float4*)&out[go + 4] = make_float4(ov[4],ov[5],ov[6],ov[7]);
    }
}

extern "C" void kernel_launch(void* const* d_in, const int* in_sizes, int n_in,
                              void* d_out, int out_size, void* d_ws, size_t ws_size,
                              hipStream_t stream) {
    (void)in_sizes; (void)n_in; (void)out_size; (void)ws_size;
    const float* x   = (const float*)d_in[0];
    const int*   nb  = (const int*)d_in[2];
    const float* tW1 = (const float*)d_in[3];
    const float* tb1 = (const float*)d_in[4];
    const float* tW2 = (const float*)d_in[5];
    const float* tb2 = (const float*)d_in[6];
    const float* tW3 = (const float*)d_in[7];
    const float* tb3 = (const float*)d_in[8];
    const float* sW1 = (const float*)d_in[9];
    const float* sb1 = (const float*)d_in[10];
    const float* sW2 = (const float*)d_in[11];
    const float* sb2 = (const float*)d_in[12];
    const float* sW3 = (const float*)d_in[13];
    const float* sb3 = (const float*)d_in[14];
    float* out = (float*)d_out;

    float* ws  = (float*)d_ws;
    float* T1r = ws;                                   // 16000*128 f32
    float* P   = ws + (size_t)NROWS * NW;              // 16000*128 f32
    float* Q   = ws + (size_t)2 * NROWS * NW;          // 16000*128 f32
    float* xxp = ws + (size_t)3 * NROWS * NW;          // 16000 f32
    int*   tk  = (int*)(ws + (size_t)3 * NROWS * NW + NROWS);   // 16000*10 int
    _Float16* xb;
    {
        size_t off_f = (size_t)3 * NROWS * NW + NROWS + (size_t)NROWS * NK;
        xb = (_Float16*)((char*)d_ws + off_f * 4);
    }
    _Float16* wt3h = xb + (size_t)NBATCH * 8 * PLANE;  // 8,388,608 f16 for xb
    _Float16* ws3h = wt3h + NC * NW;

    k_prep<<<NBATCH * 32, 256, 0, stream>>>(x, xb, xxp);
    k_wprep<<<32, 256, 0, stream>>>(tW3, wt3h, NC * NW);
    k_wprep<<<32, 256, 0, stream>>>(sW3, ws3h, NC * NW);
    k_rowgemm<<<dim3(NROWS / 32, 3), 256, 0, stream>>>(x, tW1, tb1, sW1, sb1, T1r, P, Q);
    k_topk<<<NBATCH * (NPTS / 16), 256, 0, stream>>>(xb, xxp, tk);
    k_fused<<<NROWS / 8, 256, 0, stream>>>(x, nb, tk, T1r, P, Q,
                                           tW2, tb2, sW2, sb2, wt3h, ws3h, tb3, sb3, out);
}